// Round 10
// baseline (623.922 us; speedup 1.0000x reference)
//
#include <hip/hip_runtime.h>
#include <math.h>

#define T_STEPS 30
#define BATCH   64
#define HID     1024
#define VOCABN  32000
#define G3      3072
#define ROWS    (T_STEPS * BATCH)   // 1920
#define OUT_HID_OFF ((size_t)BATCH * T_STEPS * VOCABN)  // 61,440,000
#define NBY 15
#define NBX 250
#define NPART 500

typedef __attribute__((ext_vector_type(8))) short bf16x8;
typedef __attribute__((ext_vector_type(4))) float f32x4;

__device__ __forceinline__ unsigned short f2bf(float f) {
    union { float f; unsigned u; } x; x.f = f;
    unsigned r = x.u + 0x7fffu + ((x.u >> 16) & 1u);
    return (unsigned short)(r >> 16);
}

__device__ __forceinline__ void gld_lds16(const unsigned short* g, unsigned short* l) {
    __builtin_amdgcn_global_load_lds(
        (const __attribute__((address_space(1))) unsigned*)g,
        (__attribute__((address_space(3))) unsigned*)l, 16, 0, 0);
}

// ---------------------------------------------------------------- fp32 -> bf16 (RNE)
__global__ __launch_bounds__(256) void f32_to_bf16(const float* __restrict__ src,
                                                   unsigned short* __restrict__ dst, int n4) {
    int i = blockIdx.x * 256 + threadIdx.x;
    int stride = gridDim.x * 256;
    for (; i < n4; i += stride) {
        float4 v = ((const float4*)src)[i];
        ushort4 o;
        o.x = f2bf(v.x); o.y = f2bf(v.y); o.z = f2bf(v.z); o.w = f2bf(v.w);
        ((ushort4*)dst)[i] = o;
    }
}

// ---------------------------------------------------------------- X = relu(emb[tok]) -> bf16
__global__ __launch_bounds__(256) void embed_relu_bf16(const int* __restrict__ target,
                                                       const float* __restrict__ emb,
                                                       unsigned short* __restrict__ X) {
    int bid = blockIdx.x;           // t*64 + b
    int t = bid >> 6, b = bid & 63;
    int tok = (t == 0) ? 0 : target[b * T_STEPS + (t - 1)];
    const float4* src = (const float4*)(emb + (size_t)tok * HID);
    float4 v = src[threadIdx.x];
    ushort4 o;
    o.x = f2bf(fmaxf(v.x, 0.f)); o.y = f2bf(fmaxf(v.y, 0.f));
    o.z = f2bf(fmaxf(v.z, 0.f)); o.w = f2bf(fmaxf(v.w, 0.f));
    ((ushort4*)(X + (size_t)bid * HID))[threadIdx.x] = o;
}

// ---------------------------------------------------------------- barrier flags init (64 flags)
__global__ void init_bar(unsigned int* bar) {
    if (threadIdx.x < 64) bar[threadIdx.x] = 0u;
}

// ---------------------------------------------------------------- gi GEMM (unchanged)
__global__ __launch_bounds__(256) void gemm_mfma_bt(const unsigned short* __restrict__ A,
                                                    const unsigned short* __restrict__ W,
                                                    const float* __restrict__ bias,
                                                    float* __restrict__ out,
                                                    int N, int K) {
    __shared__ unsigned short As[128 * 64];
    __shared__ unsigned short Bs[128 * 64];
    int tid  = threadIdx.x;
    int lane = tid & 63;
    int wid  = tid >> 6;
    int wm   = wid >> 1, wn = wid & 1;
    const int bM = blockIdx.y * 128;
    const int bN = blockIdx.x * 128;

    f32x4 acc[4][4];
#pragma unroll
    for (int i = 0; i < 4; ++i)
#pragma unroll
        for (int j = 0; j < 4; ++j) acc[i][j] = (f32x4){0.f, 0.f, 0.f, 0.f};

    int sr[4], sc[4];
#pragma unroll
    for (int q = 0; q < 4; ++q) {
        sr[q] = (wid * 4 + q) * 8 + (lane >> 3);
        sc[q] = (lane & 7) ^ (sr[q] & 7);
    }

    for (int kt = 0; kt < K; kt += 64) {
        __syncthreads();
#pragma unroll
        for (int q = 0; q < 4; ++q) {
            gld_lds16(A + (size_t)(bM + sr[q]) * K + kt + sc[q] * 8, As + (wid * 4 + q) * 512);
            gld_lds16(W + (size_t)(bN + sr[q]) * K + kt + sc[q] * 8, Bs + (wid * 4 + q) * 512);
        }
        __syncthreads();

#pragma unroll
        for (int ks = 0; ks < 2; ++ks) {
            bf16x8 a[4], b[4];
#pragma unroll
            for (int mf = 0; mf < 4; ++mf) {
                int r  = wm * 64 + mf * 16 + (lane & 15);
                int ch = (ks * 4 + (lane >> 4)) ^ (r & 7);
                a[mf] = *(const bf16x8*)(As + r * 64 + ch * 8);
            }
#pragma unroll
            for (int nf = 0; nf < 4; ++nf) {
                int r  = wn * 64 + nf * 16 + (lane & 15);
                int ch = (ks * 4 + (lane >> 4)) ^ (r & 7);
                b[nf] = *(const bf16x8*)(Bs + r * 64 + ch * 8);
            }
#pragma unroll
            for (int mf = 0; mf < 4; ++mf)
#pragma unroll
                for (int nf = 0; nf < 4; ++nf)
                    acc[mf][nf] = __builtin_amdgcn_mfma_f32_16x16x32_bf16(
                        a[mf], b[nf], acc[mf][nf], 0, 0, 0);
        }
    }

    int rif = (lane >> 4) * 4;
    int col = lane & 15;
#pragma unroll
    for (int mf = 0; mf < 4; ++mf) {
#pragma unroll
        for (int j = 0; j < 4; ++j) {
            int gr = bM + wm * 64 + mf * 16 + rif + j;
#pragma unroll
            for (int nf = 0; nf < 4; ++nf) {
                int gc = bN + wn * 64 + nf * 16 + col;
                out[(size_t)gr * N + gc] = acc[mf][nf][j] + bias[gc];
            }
        }
    }
}

// ---------------------------------------------------------------- logits GEMM
// single-buffer (32 KB LDS, max blocks/CU), VGPR capped to 84 via launch_bounds
// (6 waves/SIMD -- the r2 occupancy regime), panel-major grid: by = blockIdx.x
// fastest so 15 consecutive blocks reuse one 256 KB OutW panel (L2/L3-resident).
// Stats epilogue via LDS -> coalesced transposed pstatT[part][gr].
__global__ __launch_bounds__(256, 6) void gemm_logits(const unsigned short* __restrict__ A,
                                                      const unsigned short* __restrict__ W,
                                                      const float* __restrict__ bias,
                                                      float* __restrict__ out,
                                                      float2* __restrict__ pstatT) {
    __shared__ unsigned short As[128 * 64];   // 16 KB
    __shared__ unsigned short Bs[128 * 64];   // 16 KB
    __shared__ float2 sstat[4][64];           // 2 KB
    int by = blockIdx.x;                      // M-tile: FAST-varying
    int bx = blockIdx.y;                      // OutW panel: slow-varying
    const int bM = by * 128;
    const int bN = bx * 128;
    const int K = HID;

    int tid  = threadIdx.x;
    int lane = tid & 63;
    int wid  = tid >> 6;
    int wm   = wid >> 1, wn = wid & 1;

    f32x4 acc[4][4];
#pragma unroll
    for (int i = 0; i < 4; ++i)
#pragma unroll
        for (int j = 0; j < 4; ++j) acc[i][j] = (f32x4){0.f, 0.f, 0.f, 0.f};

    int sr[4], sc[4];
#pragma unroll
    for (int q = 0; q < 4; ++q) {
        sr[q] = (wid * 4 + q) * 8 + (lane >> 3);
        sc[q] = (lane & 7) ^ (sr[q] & 7);
    }

    for (int kt = 0; kt < K; kt += 64) {
        __syncthreads();
#pragma unroll
        for (int q = 0; q < 4; ++q) {
            gld_lds16(A + (size_t)(bM + sr[q]) * K + kt + sc[q] * 8, As + (wid * 4 + q) * 512);
            gld_lds16(W + (size_t)(bN + sr[q]) * K + kt + sc[q] * 8, Bs + (wid * 4 + q) * 512);
        }
        __syncthreads();

#pragma unroll
        for (int ks = 0; ks < 2; ++ks) {
            bf16x8 a[4], b[4];
#pragma unroll
            for (int mf = 0; mf < 4; ++mf) {
                int r  = wm * 64 + mf * 16 + (lane & 15);
                int ch = (ks * 4 + (lane >> 4)) ^ (r & 7);
                a[mf] = *(const bf16x8*)(As + r * 64 + ch * 8);
            }
#pragma unroll
            for (int nf = 0; nf < 4; ++nf) {
                int r  = wn * 64 + nf * 16 + (lane & 15);
                int ch = (ks * 4 + (lane >> 4)) ^ (r & 7);
                b[nf] = *(const bf16x8*)(Bs + r * 64 + ch * 8);
            }
#pragma unroll
            for (int mf = 0; mf < 4; ++mf)
#pragma unroll
                for (int nf = 0; nf < 4; ++nf)
                    acc[mf][nf] = __builtin_amdgcn_mfma_f32_16x16x32_bf16(
                        a[mf], b[nf], acc[mf][nf], 0, 0, 0);
        }
    }

    int rif = (lane >> 4) * 4;
    int col = lane & 15;
#pragma unroll
    for (int mf = 0; mf < 4; ++mf) {
#pragma unroll
        for (int j = 0; j < 4; ++j) {
            int gr = bM + wm * 64 + mf * 16 + rif + j;
            int t = gr >> 6, b = gr & 63;
            int prow = b * T_STEPS + t;
            float v[4];
            float mx = -1e30f;
#pragma unroll
            for (int nf = 0; nf < 4; ++nf) {
                int gc = bN + wn * 64 + nf * 16 + col;
                v[nf] = acc[mf][nf][j] + bias[gc];
                out[(size_t)prow * VOCABN + gc] = v[nf];
                mx = fmaxf(mx, v[nf]);
            }
#pragma unroll
            for (int off = 1; off < 16; off <<= 1) mx = fmaxf(mx, __shfl_xor(mx, off, 64));
            float se = 0.f;
#pragma unroll
            for (int nf = 0; nf < 4; ++nf) se += __expf(v[nf] - mx);
#pragma unroll
            for (int off = 1; off < 16; off <<= 1) se += __shfl_xor(se, off, 64);
            if (col == 0) sstat[wid][mf * 16 + rif + j] = make_float2(mx, se);
        }
    }
    __syncthreads();
    {
        int ws_ = tid >> 6, rl = tid & 63;
        int gr = bM + (ws_ >> 1) * 64 + rl;          // unpermuted row id
        int part = bx * 2 + (ws_ & 1);
        pstatT[(size_t)part * ROWS + gr] = sstat[ws_][rl];
    }
}

// ---------------------------------------------------------------- persistent 30-step GRU (unchanged from r8)
__global__ __launch_bounds__(256, 1) void gru_persistent(
    const unsigned short* __restrict__ h0b,   // [64][1024] bf16
    const float* __restrict__ enc_h,          // [64][1024] fp32
    const unsigned short* __restrict__ Whh,   // [3072][1024] bf16
    const float* __restrict__ b_hh,
    const float* __restrict__ gi,             // [30][64][3072] fp32
    unsigned short* __restrict__ Hall,        // [30][64][1024] bf16
    float* __restrict__ h_final,              // [64][1024] fp32
    unsigned int* __restrict__ flags)         // [64] zeroed per launch
{
    __shared__ unsigned short Wlds[48 * 1024];   // 96 KB
    int tid  = threadIdx.x;
    int lane = tid & 63;
    int wq   = tid >> 6;
    int l15  = lane & 15, l4 = lane >> 4;
    int m0   = blockIdx.x * 16;
    int b    = wq * 16 + l15;
    int mb   = m0 + l4 * 4;

    for (int i = 0; i < 24; ++i) {
        int sb = wq * 24 + i;
        int kt = sb / 3, g = sb % 3;
        const unsigned short* src =
            Whh + (size_t)(g * HID + m0 + l15) * HID + kt * 32 + l4 * 8;
        gld_lds16(src, Wlds + sb * 512);
    }

    float hp[4];
    {
        float4 h4 = *(const float4*)(enc_h + (size_t)b * HID + mb);
        hp[0] = h4.x; hp[1] = h4.y; hp[2] = h4.z; hp[3] = h4.w;
    }
    float bhr[4], bhz[4], bhn[4];
    {
        float4 r4 = *(const float4*)(b_hh + mb);
        float4 z4 = *(const float4*)(b_hh + HID + mb);
        float4 n4 = *(const float4*)(b_hh + 2 * HID + mb);
        bhr[0]=r4.x; bhr[1]=r4.y; bhr[2]=r4.z; bhr[3]=r4.w;
        bhz[0]=z4.x; bhz[1]=z4.y; bhz[2]=z4.z; bhz[3]=z4.w;
        bhn[0]=n4.x; bhn[1]=n4.y; bhn[2]=n4.z; bhn[3]=n4.w;
    }
    __syncthreads();

    int arow16 = b * 128 + l4;

    for (int t = 0; t < T_STEPS; ++t) {
        const float* gib = gi + (size_t)t * BATCH * G3 + (size_t)b * G3;
        float4 giR = *(const float4*)(gib + mb);
        float4 giZ = *(const float4*)(gib + HID + mb);
        float4 giN = *(const float4*)(gib + 2 * HID + mb);
        float gr4[4] = {giR.x, giR.y, giR.z, giR.w};
        float gz4[4] = {giZ.x, giZ.y, giZ.z, giZ.w};
        float gn4[4] = {giN.x, giN.y, giN.z, giN.w};

        if (t > 0) {
            if (tid < 64) {
                while (__hip_atomic_load(flags + tid, __ATOMIC_RELAXED,
                                         __HIP_MEMORY_SCOPE_AGENT) < (unsigned)t) {}
            }
            __builtin_amdgcn_sched_barrier(0);
            __syncthreads();
            asm volatile("" ::: "memory");
        }

        const unsigned short* Asrc = (t == 0) ? h0b : (Hall + (size_t)(t - 1) * BATCH * HID);
        const bf16x8* A16 = (const bf16x8*)Asrc;

        bf16x8 hreg[32];
#pragma unroll
        for (int kt = 0; kt < 32; ++kt) hreg[kt] = A16[arow16 + kt * 4];

        f32x4 acc[3];
#pragma unroll
        for (int g = 0; g < 3; ++g) acc[g] = (f32x4){0.f, 0.f, 0.f, 0.f};

#pragma unroll
        for (int kt = 0; kt < 32; ++kt) {
#pragma unroll
            for (int g = 0; g < 3; ++g) {
                bf16x8 wfrag = *(const bf16x8*)(Wlds + ((size_t)(kt * 3 + g) * 64 + lane) * 8);
                acc[g] = __builtin_amdgcn_mfma_f32_16x16x32_bf16(wfrag, hreg[kt], acc[g], 0, 0, 0);
            }
        }

        unsigned long long pack = 0;
#pragma unroll
        for (int j = 0; j < 4; ++j) {
            float r = 1.f / (1.f + __expf(-(gr4[j] + acc[0][j] + bhr[j])));
            float z = 1.f / (1.f + __expf(-(gz4[j] + acc[1][j] + bhz[j])));
            float e2 = __expf(2.f * (gn4[j] + r * (acc[2][j] + bhn[j])));
            float n = 1.f - 2.f / (e2 + 1.f);   // tanh
            float hnew = (1.f - z) * n + z * hp[j];
            hp[j] = hnew;
            pack |= (unsigned long long)f2bf(hnew) << (16 * j);
        }
        __hip_atomic_store((unsigned long long*)(Hall + (size_t)t * BATCH * HID +
                                                 (size_t)b * HID + mb),
                           pack, __ATOMIC_RELAXED, __HIP_MEMORY_SCOPE_AGENT);
        if (t == T_STEPS - 1) {
            float4 hf = {hp[0], hp[1], hp[2], hp[3]};
            *(float4*)(h_final + (size_t)b * HID + mb) = hf;
        }

        if (t < T_STEPS - 1) {
            __syncthreads();
            if (tid == 0)
                __hip_atomic_store(flags + blockIdx.x, (unsigned)(t + 1),
                                   __ATOMIC_RELAXED, __HIP_MEMORY_SCOPE_AGENT);
        }
    }
}

// ---------------------------------------------------------------- softmax partial reduce
__global__ __launch_bounds__(64) void lsm_reduce(const float2* __restrict__ pstatT,
                                                 float2* __restrict__ stats) {
    int lane = threadIdx.x;
    int r = blockIdx.x;                       // prow = b*30 + t
    int gr = (r % T_STEPS) * 64 + (r / T_STEPS);
    float m = -1e30f;
    for (int i = lane; i < NPART; i += 64) m = fmaxf(m, pstatT[(size_t)i * ROWS + gr].x);
#pragma unroll
    for (int off = 1; off < 64; off <<= 1) m = fmaxf(m, __shfl_xor(m, off, 64));
    float s = 0.f;
    for (int i = lane; i < NPART; i += 64) {
        float2 t = pstatT[(size_t)i * ROWS + gr];
        s += t.y * __expf(t.x - m);
    }
#pragma unroll
    for (int off = 1; off < 64; off <<= 1) s += __shfl_xor(s, off, 64);
    if (lane == 0) stats[r] = make_float2(m, logf(s));
}

// ---------------------------------------------------------------- apply: out -= mx + logZ
__global__ __launch_bounds__(256) void lsm_apply(float* __restrict__ out,
                                                 const float2* __restrict__ stats) {
    int i = blockIdx.x * 256 + threadIdx.x;
    int stride = gridDim.x * 256;
    const int total4 = ROWS * VOCABN / 4;
    for (; i < total4; i += stride) {
        int row = i / (VOCABN / 4);
        float2 st = stats[row];
        float c = st.x + st.y;
        float4 v = ((float4*)out)[i];
        v.x -= c; v.y -= c; v.z -= c; v.w -= c;
        ((float4*)out)[i] = v;
    }
}

// ----------------------------------------------------------------
extern "C" void kernel_launch(void* const* d_in, const int* in_sizes, int n_in,
                              void* d_out, int out_size, void* d_ws, size_t ws_size,
                              hipStream_t stream) {
    const float* enc_h  = (const float*)d_in[1];
    const int*   target = (const int*)d_in[2];
    const float* emb    = (const float*)d_in[3];
    const float* w_ih   = (const float*)d_in[4];
    const float* w_hh   = (const float*)d_in[5];
    const float* b_ih   = (const float*)d_in[6];
    const float* b_hh   = (const float*)d_in[7];
    const float* out_w  = (const float*)d_in[8];
    const float* out_b  = (const float*)d_in[9];
    float* out = (float*)d_out;

    char* p = (char*)d_ws;
    unsigned short* Xb   = (unsigned short*)p; p += (size_t)ROWS * HID * 2;
    unsigned short* Wih  = (unsigned short*)p; p += (size_t)G3 * HID * 2;
    unsigned short* OutW = (unsigned short*)p; p += (size_t)VOCABN * HID * 2;
    unsigned short* Hall = (unsigned short*)p; p += (size_t)ROWS * HID * 2;
    float* gi   = (float*)p; p += (size_t)ROWS * G3 * 4;
    unsigned short* Whhb = (unsigned short*)p; p += (size_t)G3 * HID * 2;
    unsigned short* h0b  = (unsigned short*)p; p += (size_t)BATCH * HID * 2;
    float2* stats = (float2*)p; p += (size_t)ROWS * 8;
    unsigned int* bar = (unsigned int*)p; p += 64 * sizeof(unsigned int);
    float2* pstatT = (float2*)Xb;   // [500][1920], 7.68 MB, overlays Xb+Wih (dead after gi GEMM)

    f32_to_bf16<<<768, 256, 0, stream>>>(w_ih, Wih, G3 * HID / 4);
    f32_to_bf16<<<768, 256, 0, stream>>>(w_hh, Whhb, G3 * HID / 4);
    f32_to_bf16<<<2048, 256, 0, stream>>>(out_w, OutW, VOCABN * HID / 4);
    f32_to_bf16<<<64, 256, 0, stream>>>(enc_h, h0b, BATCH * HID / 4);
    embed_relu_bf16<<<ROWS, 256, 0, stream>>>(target, emb, Xb);
    init_bar<<<1, 64, 0, stream>>>(bar);

    gemm_mfma_bt<<<dim3(G3 / 128, ROWS / 128), 256, 0, stream>>>(Xb, Wih, b_ih, gi, G3, HID);

    {
        const unsigned short* a0 = h0b;
        const float* a1 = enc_h;
        const unsigned short* a2 = Whhb;
        const float* a3 = b_hh;
        const float* a4 = gi;
        unsigned short* a5 = Hall;
        float* a6 = out + OUT_HID_OFF;
        unsigned int* a7 = bar;
        void* args[] = {&a0, &a1, &a2, &a3, &a4, &a5, &a6, &a7};
        hipLaunchCooperativeKernel((void*)gru_persistent, dim3(64), dim3(256),
                                   args, 0, stream);
    }

    gemm_logits<<<dim3(NBY, NBX), 256, 0, stream>>>(Hall, OutW, out_b, out, pstatT);
    lsm_reduce<<<ROWS, 64, 0, stream>>>(pstatT, stats);
    lsm_apply<<<2048, 256, 0, stream>>>(out, stats);
}

// Round 11
// 615.848 us; speedup vs baseline: 1.0131x; 1.0131x over previous
//
#include <hip/hip_runtime.h>
#include <math.h>

#define T_STEPS 30
#define BATCH   64
#define HID     1024
#define VOCABN  32000
#define G3      3072
#define ROWS    (T_STEPS * BATCH)   // 1920
#define OUT_HID_OFF ((size_t)BATCH * T_STEPS * VOCABN)  // 61,440,000
#define NBY 15
#define NBX 250

typedef __attribute__((ext_vector_type(8))) short bf16x8;
typedef __attribute__((ext_vector_type(4))) float f32x4;

__device__ __forceinline__ unsigned short f2bf(float f) {
    union { float f; unsigned u; } x; x.f = f;
    unsigned r = x.u + 0x7fffu + ((x.u >> 16) & 1u);
    return (unsigned short)(r >> 16);
}

__device__ __forceinline__ void gld_lds16(const unsigned short* g, unsigned short* l) {
    __builtin_amdgcn_global_load_lds(
        (const __attribute__((address_space(1))) unsigned*)g,
        (__attribute__((address_space(3))) unsigned*)l, 16, 0, 0);
}

// ---------------------------------------------------------------- fp32 -> bf16 (RNE)
__global__ __launch_bounds__(256) void f32_to_bf16(const float* __restrict__ src,
                                                   unsigned short* __restrict__ dst, int n4) {
    int i = blockIdx.x * 256 + threadIdx.x;
    int stride = gridDim.x * 256;
    for (; i < n4; i += stride) {
        float4 v = ((const float4*)src)[i];
        ushort4 o;
        o.x = f2bf(v.x); o.y = f2bf(v.y); o.z = f2bf(v.z); o.w = f2bf(v.w);
        ((ushort4*)dst)[i] = o;
    }
}

// ---------------------------------------------------------------- X = relu(emb[tok]) -> bf16
__global__ __launch_bounds__(256) void embed_relu_bf16(const int* __restrict__ target,
                                                       const float* __restrict__ emb,
                                                       unsigned short* __restrict__ X) {
    int bid = blockIdx.x;           // t*64 + b
    int t = bid >> 6, b = bid & 63;
    int tok = (t == 0) ? 0 : target[b * T_STEPS + (t - 1)];
    const float4* src = (const float4*)(emb + (size_t)tok * HID);
    float4 v = src[threadIdx.x];
    ushort4 o;
    o.x = f2bf(fmaxf(v.x, 0.f)); o.y = f2bf(fmaxf(v.y, 0.f));
    o.z = f2bf(fmaxf(v.z, 0.f)); o.w = f2bf(fmaxf(v.w, 0.f));
    ((ushort4*)(X + (size_t)bid * HID))[threadIdx.x] = o;
}

// ---------------------------------------------------------------- barrier flags init (64 flags)
__global__ void init_bar(unsigned int* bar) {
    if (threadIdx.x < 64) bar[threadIdx.x] = 0u;
}

// ---------------------------------------------------------------- gi GEMM (unchanged)
__global__ __launch_bounds__(256) void gemm_mfma_bt(const unsigned short* __restrict__ A,
                                                    const unsigned short* __restrict__ W,
                                                    const float* __restrict__ bias,
                                                    float* __restrict__ out,
                                                    int N, int K) {
    __shared__ unsigned short As[128 * 64];
    __shared__ unsigned short Bs[128 * 64];
    int tid  = threadIdx.x;
    int lane = tid & 63;
    int wid  = tid >> 6;
    int wm   = wid >> 1, wn = wid & 1;
    const int bM = blockIdx.y * 128;
    const int bN = blockIdx.x * 128;

    f32x4 acc[4][4];
#pragma unroll
    for (int i = 0; i < 4; ++i)
#pragma unroll
        for (int j = 0; j < 4; ++j) acc[i][j] = (f32x4){0.f, 0.f, 0.f, 0.f};

    int sr[4], sc[4];
#pragma unroll
    for (int q = 0; q < 4; ++q) {
        sr[q] = (wid * 4 + q) * 8 + (lane >> 3);
        sc[q] = (lane & 7) ^ (sr[q] & 7);
    }

    for (int kt = 0; kt < K; kt += 64) {
        __syncthreads();
#pragma unroll
        for (int q = 0; q < 4; ++q) {
            gld_lds16(A + (size_t)(bM + sr[q]) * K + kt + sc[q] * 8, As + (wid * 4 + q) * 512);
            gld_lds16(W + (size_t)(bN + sr[q]) * K + kt + sc[q] * 8, Bs + (wid * 4 + q) * 512);
        }
        __syncthreads();

#pragma unroll
        for (int ks = 0; ks < 2; ++ks) {
            bf16x8 a[4], b[4];
#pragma unroll
            for (int mf = 0; mf < 4; ++mf) {
                int r  = wm * 64 + mf * 16 + (lane & 15);
                int ch = (ks * 4 + (lane >> 4)) ^ (r & 7);
                a[mf] = *(const bf16x8*)(As + r * 64 + ch * 8);
            }
#pragma unroll
            for (int nf = 0; nf < 4; ++nf) {
                int r  = wn * 64 + nf * 16 + (lane & 15);
                int ch = (ks * 4 + (lane >> 4)) ^ (r & 7);
                b[nf] = *(const bf16x8*)(Bs + r * 64 + ch * 8);
            }
#pragma unroll
            for (int mf = 0; mf < 4; ++mf)
#pragma unroll
                for (int nf = 0; nf < 4; ++nf)
                    acc[mf][nf] = __builtin_amdgcn_mfma_f32_16x16x32_bf16(
                        a[mf], b[nf], acc[mf][nf], 0, 0, 0);
        }
    }

    int rif = (lane >> 4) * 4;
    int col = lane & 15;
#pragma unroll
    for (int mf = 0; mf < 4; ++mf) {
#pragma unroll
        for (int j = 0; j < 4; ++j) {
            int gr = bM + wm * 64 + mf * 16 + rif + j;
#pragma unroll
            for (int nf = 0; nf < 4; ++nf) {
                int gc = bN + wn * 64 + nf * 16 + col;
                out[(size_t)gr * N + gc] = acc[mf][nf][j] + bias[gc];
            }
        }
    }
}

// ---------------------------------------------------------------- logits GEMM
// EXACT r2 structure (no stats epilogue -> VGPR ~80, r2's 30% occupancy) +
// XCD-contiguous panel map: grid 3840 (=8*480), XCD i = orig&7 owns panels
// [i*32, i*32+32), its 15 M-tiles per panel consecutive -> OutW panel is
// fetched by exactly one XCD's L2, once. p >= 250 early-exits (XCD7 tail).
__global__ __launch_bounds__(256) void gemm_logits(const unsigned short* __restrict__ A,
                                                   const unsigned short* __restrict__ W,
                                                   const float* __restrict__ bias,
                                                   float* __restrict__ out) {
    __shared__ unsigned short As[128 * 64];
    __shared__ unsigned short Bs[128 * 64];
    int orig = blockIdx.x;
    int xcd = orig & 7, j = orig >> 3;
    int p = xcd * 32 + j / NBY;        // panel (N-tile)
    if (p >= NBX) return;
    int by = j % NBY;                  // M-tile, fastest within panel
    const int bM = by * 128;
    const int bN = p * 128;
    const int K = HID;

    int tid  = threadIdx.x;
    int lane = tid & 63;
    int wid  = tid >> 6;
    int wm   = wid >> 1, wn = wid & 1;

    f32x4 acc[4][4];
#pragma unroll
    for (int i = 0; i < 4; ++i)
#pragma unroll
        for (int jj = 0; jj < 4; ++jj) acc[i][jj] = (f32x4){0.f, 0.f, 0.f, 0.f};

    int sr[4], sc[4];
#pragma unroll
    for (int q = 0; q < 4; ++q) {
        sr[q] = (wid * 4 + q) * 8 + (lane >> 3);
        sc[q] = (lane & 7) ^ (sr[q] & 7);
    }

    for (int kt = 0; kt < K; kt += 64) {
        __syncthreads();
#pragma unroll
        for (int q = 0; q < 4; ++q) {
            gld_lds16(A + (size_t)(bM + sr[q]) * K + kt + sc[q] * 8, As + (wid * 4 + q) * 512);
            gld_lds16(W + (size_t)(bN + sr[q]) * K + kt + sc[q] * 8, Bs + (wid * 4 + q) * 512);
        }
        __syncthreads();

#pragma unroll
        for (int ks = 0; ks < 2; ++ks) {
            bf16x8 a[4], b[4];
#pragma unroll
            for (int mf = 0; mf < 4; ++mf) {
                int r  = wm * 64 + mf * 16 + (lane & 15);
                int ch = (ks * 4 + (lane >> 4)) ^ (r & 7);
                a[mf] = *(const bf16x8*)(As + r * 64 + ch * 8);
            }
#pragma unroll
            for (int nf = 0; nf < 4; ++nf) {
                int r  = wn * 64 + nf * 16 + (lane & 15);
                int ch = (ks * 4 + (lane >> 4)) ^ (r & 7);
                b[nf] = *(const bf16x8*)(Bs + r * 64 + ch * 8);
            }
#pragma unroll
            for (int mf = 0; mf < 4; ++mf)
#pragma unroll
                for (int nf = 0; nf < 4; ++nf)
                    acc[mf][nf] = __builtin_amdgcn_mfma_f32_16x16x32_bf16(
                        a[mf], b[nf], acc[mf][nf], 0, 0, 0);
        }
    }

    int rif = (lane >> 4) * 4;
    int col = lane & 15;
#pragma unroll
    for (int mf = 0; mf < 4; ++mf) {
#pragma unroll
        for (int jj = 0; jj < 4; ++jj) {
            int gr = bM + wm * 64 + mf * 16 + rif + jj;
            int t = gr >> 6, b = gr & 63;
            size_t rowoff = ((size_t)b * T_STEPS + t) * (size_t)VOCABN;
#pragma unroll
            for (int nf = 0; nf < 4; ++nf) {
                int gc = bN + wn * 64 + nf * 16 + col;
                out[rowoff + gc] = acc[mf][nf][jj] + bias[gc];
            }
        }
    }
}

// ---------------------------------------------------------------- persistent 30-step GRU (unchanged from r8)
__global__ __launch_bounds__(256, 1) void gru_persistent(
    const unsigned short* __restrict__ h0b,   // [64][1024] bf16
    const float* __restrict__ enc_h,          // [64][1024] fp32
    const unsigned short* __restrict__ Whh,   // [3072][1024] bf16
    const float* __restrict__ b_hh,
    const float* __restrict__ gi,             // [30][64][3072] fp32
    unsigned short* __restrict__ Hall,        // [30][64][1024] bf16
    float* __restrict__ h_final,              // [64][1024] fp32
    unsigned int* __restrict__ flags)         // [64] zeroed per launch
{
    __shared__ unsigned short Wlds[48 * 1024];   // 96 KB
    int tid  = threadIdx.x;
    int lane = tid & 63;
    int wq   = tid >> 6;
    int l15  = lane & 15, l4 = lane >> 4;
    int m0   = blockIdx.x * 16;
    int b    = wq * 16 + l15;
    int mb   = m0 + l4 * 4;

    for (int i = 0; i < 24; ++i) {
        int sb = wq * 24 + i;
        int kt = sb / 3, g = sb % 3;
        const unsigned short* src =
            Whh + (size_t)(g * HID + m0 + l15) * HID + kt * 32 + l4 * 8;
        gld_lds16(src, Wlds + sb * 512);
    }

    float hp[4];
    {
        float4 h4 = *(const float4*)(enc_h + (size_t)b * HID + mb);
        hp[0] = h4.x; hp[1] = h4.y; hp[2] = h4.z; hp[3] = h4.w;
    }
    float bhr[4], bhz[4], bhn[4];
    {
        float4 r4 = *(const float4*)(b_hh + mb);
        float4 z4 = *(const float4*)(b_hh + HID + mb);
        float4 n4 = *(const float4*)(b_hh + 2 * HID + mb);
        bhr[0]=r4.x; bhr[1]=r4.y; bhr[2]=r4.z; bhr[3]=r4.w;
        bhz[0]=z4.x; bhz[1]=z4.y; bhz[2]=z4.z; bhz[3]=z4.w;
        bhn[0]=n4.x; bhn[1]=n4.y; bhn[2]=n4.z; bhn[3]=n4.w;
    }
    __syncthreads();

    int arow16 = b * 128 + l4;

    for (int t = 0; t < T_STEPS; ++t) {
        const float* gib = gi + (size_t)t * BATCH * G3 + (size_t)b * G3;
        float4 giR = *(const float4*)(gib + mb);
        float4 giZ = *(const float4*)(gib + HID + mb);
        float4 giN = *(const float4*)(gib + 2 * HID + mb);
        float gr4[4] = {giR.x, giR.y, giR.z, giR.w};
        float gz4[4] = {giZ.x, giZ.y, giZ.z, giZ.w};
        float gn4[4] = {giN.x, giN.y, giN.z, giN.w};

        if (t > 0) {
            if (tid < 64) {
                while (__hip_atomic_load(flags + tid, __ATOMIC_RELAXED,
                                         __HIP_MEMORY_SCOPE_AGENT) < (unsigned)t) {}
            }
            __builtin_amdgcn_sched_barrier(0);
            __syncthreads();
            asm volatile("" ::: "memory");
        }

        const unsigned short* Asrc = (t == 0) ? h0b : (Hall + (size_t)(t - 1) * BATCH * HID);
        const bf16x8* A16 = (const bf16x8*)Asrc;

        bf16x8 hreg[32];
#pragma unroll
        for (int kt = 0; kt < 32; ++kt) hreg[kt] = A16[arow16 + kt * 4];

        f32x4 acc[3];
#pragma unroll
        for (int g = 0; g < 3; ++g) acc[g] = (f32x4){0.f, 0.f, 0.f, 0.f};

#pragma unroll
        for (int kt = 0; kt < 32; ++kt) {
#pragma unroll
            for (int g = 0; g < 3; ++g) {
                bf16x8 wfrag = *(const bf16x8*)(Wlds + ((size_t)(kt * 3 + g) * 64 + lane) * 8);
                acc[g] = __builtin_amdgcn_mfma_f32_16x16x32_bf16(wfrag, hreg[kt], acc[g], 0, 0, 0);
            }
        }

        unsigned long long pack = 0;
#pragma unroll
        for (int j = 0; j < 4; ++j) {
            float r = 1.f / (1.f + __expf(-(gr4[j] + acc[0][j] + bhr[j])));
            float z = 1.f / (1.f + __expf(-(gz4[j] + acc[1][j] + bhz[j])));
            float e2 = __expf(2.f * (gn4[j] + r * (acc[2][j] + bhn[j])));
            float n = 1.f - 2.f / (e2 + 1.f);   // tanh
            float hnew = (1.f - z) * n + z * hp[j];
            hp[j] = hnew;
            pack |= (unsigned long long)f2bf(hnew) << (16 * j);
        }
        __hip_atomic_store((unsigned long long*)(Hall + (size_t)t * BATCH * HID +
                                                 (size_t)b * HID + mb),
                           pack, __ATOMIC_RELAXED, __HIP_MEMORY_SCOPE_AGENT);
        if (t == T_STEPS - 1) {
            float4 hf = {hp[0], hp[1], hp[2], hp[3]};
            *(float4*)(h_final + (size_t)b * HID + mb) = hf;
        }

        if (t < T_STEPS - 1) {
            __syncthreads();
            if (tid == 0)
                __hip_atomic_store(flags + blockIdx.x, (unsigned)(t + 1),
                                   __ATOMIC_RELAXED, __HIP_MEMORY_SCOPE_AGENT);
        }
    }
}

// ---------------------------------------------------------------- stats: one block per row,
// single streaming pass, online (max, sumexp) -> stats[row] = (mx, log(sum))
__global__ __launch_bounds__(256) void lsm_stats(const float* __restrict__ out,
                                                 float2* __restrict__ stats) {
    const float4* p = (const float4*)(out + (size_t)blockIdx.x * VOCABN);
    int tid = threadIdx.x;
    int lane = tid & 63, w = tid >> 6;
    __shared__ float2 sred[4];

    float m = -1e30f, s = 0.f;
    for (int i = tid; i < VOCABN / 4; i += 256) {
        float4 v = p[i];
        float cm = fmaxf(fmaxf(v.x, v.y), fmaxf(v.z, v.w));
        if (cm > m) { s *= __expf(m - cm); m = cm; }
        s += __expf(v.x - m) + __expf(v.y - m) + __expf(v.z - m) + __expf(v.w - m);
    }
#pragma unroll
    for (int off = 1; off < 64; off <<= 1) {
        float om = __shfl_xor(m, off, 64);
        float os = __shfl_xor(s, off, 64);
        float nm = fmaxf(m, om);
        s = s * __expf(m - nm) + os * __expf(om - nm);
        m = nm;
    }
    if (lane == 0) sred[w] = make_float2(m, s);
    __syncthreads();
    if (tid == 0) {
        float fm = sred[0].x, fs = sred[0].y;
#pragma unroll
        for (int k = 1; k < 4; ++k) {
            float om = sred[k].x, os = sred[k].y;
            float nm = fmaxf(fm, om);
            fs = fs * __expf(fm - nm) + os * __expf(om - nm);
            fm = nm;
        }
        stats[blockIdx.x] = make_float2(fm, logf(fs));
    }
}

// ---------------------------------------------------------------- apply: out -= mx + logZ
__global__ __launch_bounds__(256) void lsm_apply(float* __restrict__ out,
                                                 const float2* __restrict__ stats) {
    int i = blockIdx.x * 256 + threadIdx.x;
    int stride = gridDim.x * 256;
    const int total4 = ROWS * VOCABN / 4;
    for (; i < total4; i += stride) {
        int row = i / (VOCABN / 4);
        float2 st = stats[row];
        float c = st.x + st.y;
        float4 v = ((float4*)out)[i];
        v.x -= c; v.y -= c; v.z -= c; v.w -= c;
        ((float4*)out)[i] = v;
    }
}

// ----------------------------------------------------------------
extern "C" void kernel_launch(void* const* d_in, const int* in_sizes, int n_in,
                              void* d_out, int out_size, void* d_ws, size_t ws_size,
                              hipStream_t stream) {
    const float* enc_h  = (const float*)d_in[1];
    const int*   target = (const int*)d_in[2];
    const float* emb    = (const float*)d_in[3];
    const float* w_ih   = (const float*)d_in[4];
    const float* w_hh   = (const float*)d_in[5];
    const float* b_ih   = (const float*)d_in[6];
    const float* b_hh   = (const float*)d_in[7];
    const float* out_w  = (const float*)d_in[8];
    const float* out_b  = (const float*)d_in[9];
    float* out = (float*)d_out;

    char* p = (char*)d_ws;
    unsigned short* Xb   = (unsigned short*)p; p += (size_t)ROWS * HID * 2;
    unsigned short* Wih  = (unsigned short*)p; p += (size_t)G3 * HID * 2;
    unsigned short* OutW = (unsigned short*)p; p += (size_t)VOCABN * HID * 2;
    unsigned short* Hall = (unsigned short*)p; p += (size_t)ROWS * HID * 2;
    float* gi   = (float*)p; p += (size_t)ROWS * G3 * 4;
    unsigned short* Whhb = (unsigned short*)p; p += (size_t)G3 * HID * 2;
    unsigned short* h0b  = (unsigned short*)p; p += (size_t)BATCH * HID * 2;
    float2* stats = (float2*)p; p += (size_t)ROWS * 8;
    unsigned int* bar = (unsigned int*)p; p += 64 * sizeof(unsigned int);

    f32_to_bf16<<<768, 256, 0, stream>>>(w_ih, Wih, G3 * HID / 4);
    f32_to_bf16<<<768, 256, 0, stream>>>(w_hh, Whhb, G3 * HID / 4);
    f32_to_bf16<<<2048, 256, 0, stream>>>(out_w, OutW, VOCABN * HID / 4);
    f32_to_bf16<<<64, 256, 0, stream>>>(enc_h, h0b, BATCH * HID / 4);
    embed_relu_bf16<<<ROWS, 256, 0, stream>>>(target, emb, Xb);
    init_bar<<<1, 64, 0, stream>>>(bar);

    gemm_mfma_bt<<<dim3(G3 / 128, ROWS / 128), 256, 0, stream>>>(Xb, Wih, b_ih, gi, G3, HID);

    {
        const unsigned short* a0 = h0b;
        const float* a1 = enc_h;
        const unsigned short* a2 = Whhb;
        const float* a3 = b_hh;
        const float* a4 = gi;
        unsigned short* a5 = Hall;
        float* a6 = out + OUT_HID_OFF;
        unsigned int* a7 = bar;
        void* args[] = {&a0, &a1, &a2, &a3, &a4, &a5, &a6, &a7};
        hipLaunchCooperativeKernel((void*)gru_persistent, dim3(64), dim3(256),
                                   args, 0, stream);
    }

    gemm_logits<<<3840, 256, 0, stream>>>(Hall, OutW, out_b, out);
    lsm_stats<<<ROWS, 256, 0, stream>>>(out, stats);
    lsm_apply<<<2048, 256, 0, stream>>>(out, stats);
}

// Round 12
// 613.290 us; speedup vs baseline: 1.0173x; 1.0042x over previous
//
#include <hip/hip_runtime.h>
#include <math.h>

#define T_STEPS 30
#define BATCH   64
#define HID     1024
#define VOCABN  32000
#define G3      3072
#define ROWS    (T_STEPS * BATCH)   // 1920
#define OUT_HID_OFF ((size_t)BATCH * T_STEPS * VOCABN)  // 61,440,000
#define NBY 15
#define NBX 250
#define NPART 500

typedef __attribute__((ext_vector_type(8))) short bf16x8;
typedef __attribute__((ext_vector_type(4))) float f32x4;

__device__ __forceinline__ unsigned short f2bf(float f) {
    union { float f; unsigned u; } x; x.f = f;
    unsigned r = x.u + 0x7fffu + ((x.u >> 16) & 1u);
    return (unsigned short)(r >> 16);
}

__device__ __forceinline__ void gld_lds16(const unsigned short* g, unsigned short* l) {
    __builtin_amdgcn_global_load_lds(
        (const __attribute__((address_space(1))) unsigned*)g,
        (__attribute__((address_space(3))) unsigned*)l, 16, 0, 0);
}

// ---------------------------------------------------------------- fp32 -> bf16 (RNE)
__global__ __launch_bounds__(256) void f32_to_bf16(const float* __restrict__ src,
                                                   unsigned short* __restrict__ dst, int n4) {
    int i = blockIdx.x * 256 + threadIdx.x;
    int stride = gridDim.x * 256;
    for (; i < n4; i += stride) {
        float4 v = ((const float4*)src)[i];
        ushort4 o;
        o.x = f2bf(v.x); o.y = f2bf(v.y); o.z = f2bf(v.z); o.w = f2bf(v.w);
        ((ushort4*)dst)[i] = o;
    }
}

// ---------------------------------------------------------------- X = relu(emb[tok]) -> bf16
__global__ __launch_bounds__(256) void embed_relu_bf16(const int* __restrict__ target,
                                                       const float* __restrict__ emb,
                                                       unsigned short* __restrict__ X) {
    int bid = blockIdx.x;           // t*64 + b
    int t = bid >> 6, b = bid & 63;
    int tok = (t == 0) ? 0 : target[b * T_STEPS + (t - 1)];
    const float4* src = (const float4*)(emb + (size_t)tok * HID);
    float4 v = src[threadIdx.x];
    ushort4 o;
    o.x = f2bf(fmaxf(v.x, 0.f)); o.y = f2bf(fmaxf(v.y, 0.f));
    o.z = f2bf(fmaxf(v.z, 0.f)); o.w = f2bf(fmaxf(v.w, 0.f));
    ((ushort4*)(X + (size_t)bid * HID))[threadIdx.x] = o;
}

// ---------------------------------------------------------------- barrier flags init (64 flags)
__global__ void init_bar(unsigned int* bar) {
    if (threadIdx.x < 64) bar[threadIdx.x] = 0u;
}

// ---------------------------------------------------------------- gi GEMM (unchanged)
__global__ __launch_bounds__(256) void gemm_mfma_bt(const unsigned short* __restrict__ A,
                                                    const unsigned short* __restrict__ W,
                                                    const float* __restrict__ bias,
                                                    float* __restrict__ out,
                                                    int N, int K) {
    __shared__ unsigned short As[128 * 64];
    __shared__ unsigned short Bs[128 * 64];
    int tid  = threadIdx.x;
    int lane = tid & 63;
    int wid  = tid >> 6;
    int wm   = wid >> 1, wn = wid & 1;
    const int bM = blockIdx.y * 128;
    const int bN = blockIdx.x * 128;

    f32x4 acc[4][4];
#pragma unroll
    for (int i = 0; i < 4; ++i)
#pragma unroll
        for (int j = 0; j < 4; ++j) acc[i][j] = (f32x4){0.f, 0.f, 0.f, 0.f};

    int sr[4], sc[4];
#pragma unroll
    for (int q = 0; q < 4; ++q) {
        sr[q] = (wid * 4 + q) * 8 + (lane >> 3);
        sc[q] = (lane & 7) ^ (sr[q] & 7);
    }

    for (int kt = 0; kt < K; kt += 64) {
        __syncthreads();
#pragma unroll
        for (int q = 0; q < 4; ++q) {
            gld_lds16(A + (size_t)(bM + sr[q]) * K + kt + sc[q] * 8, As + (wid * 4 + q) * 512);
            gld_lds16(W + (size_t)(bN + sr[q]) * K + kt + sc[q] * 8, Bs + (wid * 4 + q) * 512);
        }
        __syncthreads();

#pragma unroll
        for (int ks = 0; ks < 2; ++ks) {
            bf16x8 a[4], b[4];
#pragma unroll
            for (int mf = 0; mf < 4; ++mf) {
                int r  = wm * 64 + mf * 16 + (lane & 15);
                int ch = (ks * 4 + (lane >> 4)) ^ (r & 7);
                a[mf] = *(const bf16x8*)(As + r * 64 + ch * 8);
            }
#pragma unroll
            for (int nf = 0; nf < 4; ++nf) {
                int r  = wn * 64 + nf * 16 + (lane & 15);
                int ch = (ks * 4 + (lane >> 4)) ^ (r & 7);
                b[nf] = *(const bf16x8*)(Bs + r * 64 + ch * 8);
            }
#pragma unroll
            for (int mf = 0; mf < 4; ++mf)
#pragma unroll
                for (int nf = 0; nf < 4; ++nf)
                    acc[mf][nf] = __builtin_amdgcn_mfma_f32_16x16x32_bf16(
                        a[mf], b[nf], acc[mf][nf], 0, 0, 0);
        }
    }

    int rif = (lane >> 4) * 4;
    int col = lane & 15;
#pragma unroll
    for (int mf = 0; mf < 4; ++mf) {
#pragma unroll
        for (int j = 0; j < 4; ++j) {
            int gr = bM + wm * 64 + mf * 16 + rif + j;
#pragma unroll
            for (int nf = 0; nf < 4; ++nf) {
                int gc = bN + wn * 64 + nf * 16 + col;
                out[(size_t)gr * N + gc] = acc[mf][nf][j] + bias[gc];
            }
        }
    }
}

// ---------------------------------------------------------------- logits GEMM
// XCD panel map (r11) + 2-deep counted-vmcnt pipeline (T4: raw s_barrier, never
// drain vmcnt to 0 in the loop) + LDS-coalesced stats epilogue -> pstatT.
// Tile t lives in buf t&1; each wave has 8 gld_lds in flight per staged tile.
__global__ __launch_bounds__(256) void gemm_logits(const unsigned short* __restrict__ A,
                                                   const unsigned short* __restrict__ W,
                                                   const float* __restrict__ bias,
                                                   float* __restrict__ out,
                                                   float2* __restrict__ pstatT) {
    __shared__ unsigned short As[2][128 * 64];   // 16 KB x2
    __shared__ unsigned short Bs[2][128 * 64];   // 16 KB x2
    __shared__ float2 sstat[4][64];              // 2 KB
    int orig = blockIdx.x;
    int xcd = orig & 7, j = orig >> 3;
    int p = xcd * 32 + j / NBY;        // panel (N-tile): one XCD owns 32 panels
    if (p >= NBX) return;
    int by = j % NBY;                  // M-tile, fastest within panel
    const int bM = by * 128;
    const int bN = p * 128;

    int tid  = threadIdx.x;
    int lane = tid & 63;
    int wid  = tid >> 6;
    int wm   = wid >> 1, wn = wid & 1;

    f32x4 acc[4][4];
#pragma unroll
    for (int i = 0; i < 4; ++i)
#pragma unroll
        for (int jj = 0; jj < 4; ++jj) acc[i][jj] = (f32x4){0.f, 0.f, 0.f, 0.f};

    int sr[4], sc[4];
#pragma unroll
    for (int q = 0; q < 4; ++q) {
        sr[q] = (wid * 4 + q) * 8 + (lane >> 3);
        sc[q] = (lane & 7) ^ (sr[q] & 7);
    }

    auto stage = [&](int buf, int kt16) {
        int kt = kt16 * 64;
#pragma unroll
        for (int q = 0; q < 4; ++q) {
            gld_lds16(A + (size_t)(bM + sr[q]) * HID + kt + sc[q] * 8,
                      &As[buf][(wid * 4 + q) * 512]);
            gld_lds16(W + (size_t)(bN + sr[q]) * HID + kt + sc[q] * 8,
                      &Bs[buf][(wid * 4 + q) * 512]);
        }
    };
    auto compute = [&](int buf) {
#pragma unroll
        for (int ks = 0; ks < 2; ++ks) {
            bf16x8 a[4], b[4];
#pragma unroll
            for (int mf = 0; mf < 4; ++mf) {
                int r  = wm * 64 + mf * 16 + (lane & 15);
                int ch = (ks * 4 + (lane >> 4)) ^ (r & 7);
                a[mf] = *(const bf16x8*)(&As[buf][r * 64 + ch * 8]);
            }
#pragma unroll
            for (int nf = 0; nf < 4; ++nf) {
                int r  = wn * 64 + nf * 16 + (lane & 15);
                int ch = (ks * 4 + (lane >> 4)) ^ (r & 7);
                b[nf] = *(const bf16x8*)(&Bs[buf][r * 64 + ch * 8]);
            }
#pragma unroll
            for (int mf = 0; mf < 4; ++mf)
#pragma unroll
                for (int nf = 0; nf < 4; ++nf)
                    acc[mf][nf] = __builtin_amdgcn_mfma_f32_16x16x32_bf16(
                        a[mf], b[nf], acc[mf][nf], 0, 0, 0);
        }
    };

    stage(0, 0);
    stage(1, 1);                        // 16 loads in flight per wave
#pragma unroll 1
    for (int k = 0; k < 15; ++k) {
        asm volatile("s_waitcnt vmcnt(8)" ::: "memory");   // own tile-k loads landed
        __builtin_amdgcn_s_barrier();                      // all waves' tile-k landed
        __builtin_amdgcn_sched_barrier(0);
        compute(k & 1);
        __builtin_amdgcn_s_barrier();                      // all waves done reading buf k&1
        __builtin_amdgcn_sched_barrier(0);
        if (k < 14) stage(k & 1, k + 2);                   // overlaps next iteration
    }
    asm volatile("s_waitcnt vmcnt(0)" ::: "memory");
    __builtin_amdgcn_s_barrier();
    compute(1);                         // tile 15

    int rif = (lane >> 4) * 4;
    int col = lane & 15;
#pragma unroll
    for (int mf = 0; mf < 4; ++mf) {
#pragma unroll
        for (int jj = 0; jj < 4; ++jj) {
            int gr = bM + wm * 64 + mf * 16 + rif + jj;
            int t = gr >> 6, b = gr & 63;
            size_t rowoff = ((size_t)b * T_STEPS + t) * (size_t)VOCABN;
            float v[4];
            float mx = -1e30f;
#pragma unroll
            for (int nf = 0; nf < 4; ++nf) {
                int gc = bN + wn * 64 + nf * 16 + col;
                v[nf] = acc[mf][nf][jj] + bias[gc];
                out[rowoff + gc] = v[nf];
                mx = fmaxf(mx, v[nf]);
            }
#pragma unroll
            for (int off = 1; off < 16; off <<= 1) mx = fmaxf(mx, __shfl_xor(mx, off, 64));
            float se = 0.f;
#pragma unroll
            for (int nf = 0; nf < 4; ++nf) se += __expf(v[nf] - mx);
#pragma unroll
            for (int off = 1; off < 16; off <<= 1) se += __shfl_xor(se, off, 64);
            if (col == 0) sstat[wid][mf * 16 + rif + jj] = make_float2(mx, se);
        }
    }
    __syncthreads();
    {
        int ws_ = tid >> 6, rl = tid & 63;
        int gr = bM + (ws_ >> 1) * 64 + rl;          // unpermuted row id
        int part = p * 2 + (ws_ & 1);
        pstatT[(size_t)part * ROWS + gr] = sstat[ws_][rl];
    }
}

// ---------------------------------------------------------------- persistent 30-step GRU (unchanged from r8)
__global__ __launch_bounds__(256, 1) void gru_persistent(
    const unsigned short* __restrict__ h0b,   // [64][1024] bf16
    const float* __restrict__ enc_h,          // [64][1024] fp32
    const unsigned short* __restrict__ Whh,   // [3072][1024] bf16
    const float* __restrict__ b_hh,
    const float* __restrict__ gi,             // [30][64][3072] fp32
    unsigned short* __restrict__ Hall,        // [30][64][1024] bf16
    float* __restrict__ h_final,              // [64][1024] fp32
    unsigned int* __restrict__ flags)         // [64] zeroed per launch
{
    __shared__ unsigned short Wlds[48 * 1024];   // 96 KB
    int tid  = threadIdx.x;
    int lane = tid & 63;
    int wq   = tid >> 6;
    int l15  = lane & 15, l4 = lane >> 4;
    int m0   = blockIdx.x * 16;
    int b    = wq * 16 + l15;
    int mb   = m0 + l4 * 4;

    for (int i = 0; i < 24; ++i) {
        int sb = wq * 24 + i;
        int kt = sb / 3, g = sb % 3;
        const unsigned short* src =
            Whh + (size_t)(g * HID + m0 + l15) * HID + kt * 32 + l4 * 8;
        gld_lds16(src, Wlds + sb * 512);
    }

    float hp[4];
    {
        float4 h4 = *(const float4*)(enc_h + (size_t)b * HID + mb);
        hp[0] = h4.x; hp[1] = h4.y; hp[2] = h4.z; hp[3] = h4.w;
    }
    float bhr[4], bhz[4], bhn[4];
    {
        float4 r4 = *(const float4*)(b_hh + mb);
        float4 z4 = *(const float4*)(b_hh + HID + mb);
        float4 n4 = *(const float4*)(b_hh + 2 * HID + mb);
        bhr[0]=r4.x; bhr[1]=r4.y; bhr[2]=r4.z; bhr[3]=r4.w;
        bhz[0]=z4.x; bhz[1]=z4.y; bhz[2]=z4.z; bhz[3]=z4.w;
        bhn[0]=n4.x; bhn[1]=n4.y; bhn[2]=n4.z; bhn[3]=n4.w;
    }
    __syncthreads();

    int arow16 = b * 128 + l4;

    for (int t = 0; t < T_STEPS; ++t) {
        const float* gib = gi + (size_t)t * BATCH * G3 + (size_t)b * G3;
        float4 giR = *(const float4*)(gib + mb);
        float4 giZ = *(const float4*)(gib + HID + mb);
        float4 giN = *(const float4*)(gib + 2 * HID + mb);
        float gr4[4] = {giR.x, giR.y, giR.z, giR.w};
        float gz4[4] = {giZ.x, giZ.y, giZ.z, giZ.w};
        float gn4[4] = {giN.x, giN.y, giN.z, giN.w};

        if (t > 0) {
            if (tid < 64) {
                while (__hip_atomic_load(flags + tid, __ATOMIC_RELAXED,
                                         __HIP_MEMORY_SCOPE_AGENT) < (unsigned)t) {}
            }
            __builtin_amdgcn_sched_barrier(0);
            __syncthreads();
            asm volatile("" ::: "memory");
        }

        const unsigned short* Asrc = (t == 0) ? h0b : (Hall + (size_t)(t - 1) * BATCH * HID);
        const bf16x8* A16 = (const bf16x8*)Asrc;

        bf16x8 hreg[32];
#pragma unroll
        for (int kt = 0; kt < 32; ++kt) hreg[kt] = A16[arow16 + kt * 4];

        f32x4 acc[3];
#pragma unroll
        for (int g = 0; g < 3; ++g) acc[g] = (f32x4){0.f, 0.f, 0.f, 0.f};

#pragma unroll
        for (int kt = 0; kt < 32; ++kt) {
#pragma unroll
            for (int g = 0; g < 3; ++g) {
                bf16x8 wfrag = *(const bf16x8*)(Wlds + ((size_t)(kt * 3 + g) * 64 + lane) * 8);
                acc[g] = __builtin_amdgcn_mfma_f32_16x16x32_bf16(wfrag, hreg[kt], acc[g], 0, 0, 0);
            }
        }

        unsigned long long pack = 0;
#pragma unroll
        for (int j = 0; j < 4; ++j) {
            float r = 1.f / (1.f + __expf(-(gr4[j] + acc[0][j] + bhr[j])));
            float z = 1.f / (1.f + __expf(-(gz4[j] + acc[1][j] + bhz[j])));
            float e2 = __expf(2.f * (gn4[j] + r * (acc[2][j] + bhn[j])));
            float n = 1.f - 2.f / (e2 + 1.f);   // tanh
            float hnew = (1.f - z) * n + z * hp[j];
            hp[j] = hnew;
            pack |= (unsigned long long)f2bf(hnew) << (16 * j);
        }
        __hip_atomic_store((unsigned long long*)(Hall + (size_t)t * BATCH * HID +
                                                 (size_t)b * HID + mb),
                           pack, __ATOMIC_RELAXED, __HIP_MEMORY_SCOPE_AGENT);
        if (t == T_STEPS - 1) {
            float4 hf = {hp[0], hp[1], hp[2], hp[3]};
            *(float4*)(h_final + (size_t)b * HID + mb) = hf;
        }

        if (t < T_STEPS - 1) {
            __syncthreads();
            if (tid == 0)
                __hip_atomic_store(flags + blockIdx.x, (unsigned)(t + 1),
                                   __ATOMIC_RELAXED, __HIP_MEMORY_SCOPE_AGENT);
        }
    }
}

// ---------------------------------------------------------------- softmax partial reduce
// pstatT layout [NPART][ROWS] indexed by UNPERMUTED gr; stats indexed by prow.
__global__ __launch_bounds__(64) void lsm_reduce(const float2* __restrict__ pstatT,
                                                 float2* __restrict__ stats) {
    int lane = threadIdx.x;
    int r = blockIdx.x;                       // prow = b*30 + t
    int gr = (r % T_STEPS) * 64 + (r / T_STEPS);
    float m = -1e30f;
    for (int i = lane; i < NPART; i += 64) m = fmaxf(m, pstatT[(size_t)i * ROWS + gr].x);
#pragma unroll
    for (int off = 1; off < 64; off <<= 1) m = fmaxf(m, __shfl_xor(m, off, 64));
    float s = 0.f;
    for (int i = lane; i < NPART; i += 64) {
        float2 t = pstatT[(size_t)i * ROWS + gr];
        s += t.y * __expf(t.x - m);
    }
#pragma unroll
    for (int off = 1; off < 64; off <<= 1) s += __shfl_xor(s, off, 64);
    if (lane == 0) stats[r] = make_float2(m, logf(s));
}

// ---------------------------------------------------------------- apply: out -= mx + logZ
__global__ __launch_bounds__(256) void lsm_apply(float* __restrict__ out,
                                                 const float2* __restrict__ stats) {
    int i = blockIdx.x * 256 + threadIdx.x;
    int stride = gridDim.x * 256;
    const int total4 = ROWS * VOCABN / 4;
    for (; i < total4; i += stride) {
        int row = i / (VOCABN / 4);
        float2 st = stats[row];
        float c = st.x + st.y;
        float4 v = ((float4*)out)[i];
        v.x -= c; v.y -= c; v.z -= c; v.w -= c;
        ((float4*)out)[i] = v;
    }
}

// ----------------------------------------------------------------
extern "C" void kernel_launch(void* const* d_in, const int* in_sizes, int n_in,
                              void* d_out, int out_size, void* d_ws, size_t ws_size,
                              hipStream_t stream) {
    const float* enc_h  = (const float*)d_in[1];
    const int*   target = (const int*)d_in[2];
    const float* emb    = (const float*)d_in[3];
    const float* w_ih   = (const float*)d_in[4];
    const float* w_hh   = (const float*)d_in[5];
    const float* b_ih   = (const float*)d_in[6];
    const float* b_hh   = (const float*)d_in[7];
    const float* out_w  = (const float*)d_in[8];
    const float* out_b  = (const float*)d_in[9];
    float* out = (float*)d_out;

    char* p = (char*)d_ws;
    unsigned short* Xb   = (unsigned short*)p; p += (size_t)ROWS * HID * 2;
    unsigned short* Wih  = (unsigned short*)p; p += (size_t)G3 * HID * 2;
    unsigned short* OutW = (unsigned short*)p; p += (size_t)VOCABN * HID * 2;
    unsigned short* Hall = (unsigned short*)p; p += (size_t)ROWS * HID * 2;
    float* gi   = (float*)p; p += (size_t)ROWS * G3 * 4;
    unsigned short* Whhb = (unsigned short*)p; p += (size_t)G3 * HID * 2;
    unsigned short* h0b  = (unsigned short*)p; p += (size_t)BATCH * HID * 2;
    float2* stats = (float2*)p; p += (size_t)ROWS * 8;
    unsigned int* bar = (unsigned int*)p; p += 64 * sizeof(unsigned int);
    float2* pstatT = (float2*)Xb;   // [500][1920] = 7.68 MB, overlays Xb+Wih (dead after gi GEMM)

    f32_to_bf16<<<768, 256, 0, stream>>>(w_ih, Wih, G3 * HID / 4);
    f32_to_bf16<<<768, 256, 0, stream>>>(w_hh, Whhb, G3 * HID / 4);
    f32_to_bf16<<<2048, 256, 0, stream>>>(out_w, OutW, VOCABN * HID / 4);
    f32_to_bf16<<<64, 256, 0, stream>>>(enc_h, h0b, BATCH * HID / 4);
    embed_relu_bf16<<<ROWS, 256, 0, stream>>>(target, emb, Xb);
    init_bar<<<1, 64, 0, stream>>>(bar);

    gemm_mfma_bt<<<dim3(G3 / 128, ROWS / 128), 256, 0, stream>>>(Xb, Wih, b_ih, gi, G3, HID);

    {
        const unsigned short* a0 = h0b;
        const float* a1 = enc_h;
        const unsigned short* a2 = Whhb;
        const float* a3 = b_hh;
        const float* a4 = gi;
        unsigned short* a5 = Hall;
        float* a6 = out + OUT_HID_OFF;
        unsigned int* a7 = bar;
        void* args[] = {&a0, &a1, &a2, &a3, &a4, &a5, &a6, &a7};
        hipLaunchCooperativeKernel((void*)gru_persistent, dim3(64), dim3(256),
                                   args, 0, stream);
    }

    gemm_logits<<<3840, 256, 0, stream>>>(Hall, OutW, out_b, out, pstatT);
    lsm_reduce<<<ROWS, 64, 0, stream>>>(pstatT, stats);
    lsm_apply<<<2048, 256, 0, stream>>>(out, stats);
}

// Round 13
// 602.820 us; speedup vs baseline: 1.0350x; 1.0174x over previous
//
#include <hip/hip_runtime.h>
#include <math.h>

#define T_STEPS 30
#define BATCH   64
#define HID     1024
#define VOCABN  32000
#define G3      3072
#define ROWS    (T_STEPS * BATCH)   // 1920
#define OUT_HID_OFF ((size_t)BATCH * T_STEPS * VOCABN)  // 61,440,000
#define NBY 15
#define NBX 250

typedef __attribute__((ext_vector_type(8))) short bf16x8;
typedef __attribute__((ext_vector_type(4))) float f32x4;

__device__ __forceinline__ unsigned short f2bf(float f) {
    union { float f; unsigned u; } x; x.f = f;
    unsigned r = x.u + 0x7fffu + ((x.u >> 16) & 1u);
    return (unsigned short)(r >> 16);
}

__device__ __forceinline__ void gld_lds16(const unsigned short* g, unsigned short* l) {
    __builtin_amdgcn_global_load_lds(
        (const __attribute__((address_space(1))) unsigned*)g,
        (__attribute__((address_space(3))) unsigned*)l, 16, 0, 0);
}

// ---------------------------------------------------------------- fp32 -> bf16 (RNE)
__global__ __launch_bounds__(256) void f32_to_bf16(const float* __restrict__ src,
                                                   unsigned short* __restrict__ dst, int n4) {
    int i = blockIdx.x * 256 + threadIdx.x;
    int stride = gridDim.x * 256;
    for (; i < n4; i += stride) {
        float4 v = ((const float4*)src)[i];
        ushort4 o;
        o.x = f2bf(v.x); o.y = f2bf(v.y); o.z = f2bf(v.z); o.w = f2bf(v.w);
        ((ushort4*)dst)[i] = o;
    }
}

// ---------------------------------------------------------------- X = relu(emb[tok]) -> bf16
__global__ __launch_bounds__(256) void embed_relu_bf16(const int* __restrict__ target,
                                                       const float* __restrict__ emb,
                                                       unsigned short* __restrict__ X) {
    int bid = blockIdx.x;           // t*64 + b
    int t = bid >> 6, b = bid & 63;
    int tok = (t == 0) ? 0 : target[b * T_STEPS + (t - 1)];
    const float4* src = (const float4*)(emb + (size_t)tok * HID);
    float4 v = src[threadIdx.x];
    ushort4 o;
    o.x = f2bf(fmaxf(v.x, 0.f)); o.y = f2bf(fmaxf(v.y, 0.f));
    o.z = f2bf(fmaxf(v.z, 0.f)); o.w = f2bf(fmaxf(v.w, 0.f));
    ((ushort4*)(X + (size_t)bid * HID))[threadIdx.x] = o;
}

// ---------------------------------------------------------------- barrier flags init (64 flags)
__global__ void init_bar(unsigned int* bar) {
    if (threadIdx.x < 64) bar[threadIdx.x] = 0u;
}

// ---------------------------------------------------------------- gi GEMM (unchanged)
__global__ __launch_bounds__(256) void gemm_mfma_bt(const unsigned short* __restrict__ A,
                                                    const unsigned short* __restrict__ W,
                                                    const float* __restrict__ bias,
                                                    float* __restrict__ out,
                                                    int N, int K) {
    __shared__ unsigned short As[128 * 64];
    __shared__ unsigned short Bs[128 * 64];
    int tid  = threadIdx.x;
    int lane = tid & 63;
    int wid  = tid >> 6;
    int wm   = wid >> 1, wn = wid & 1;
    const int bM = blockIdx.y * 128;
    const int bN = blockIdx.x * 128;

    f32x4 acc[4][4];
#pragma unroll
    for (int i = 0; i < 4; ++i)
#pragma unroll
        for (int j = 0; j < 4; ++j) acc[i][j] = (f32x4){0.f, 0.f, 0.f, 0.f};

    int sr[4], sc[4];
#pragma unroll
    for (int q = 0; q < 4; ++q) {
        sr[q] = (wid * 4 + q) * 8 + (lane >> 3);
        sc[q] = (lane & 7) ^ (sr[q] & 7);
    }

    for (int kt = 0; kt < K; kt += 64) {
        __syncthreads();
#pragma unroll
        for (int q = 0; q < 4; ++q) {
            gld_lds16(A + (size_t)(bM + sr[q]) * K + kt + sc[q] * 8, As + (wid * 4 + q) * 512);
            gld_lds16(W + (size_t)(bN + sr[q]) * K + kt + sc[q] * 8, Bs + (wid * 4 + q) * 512);
        }
        __syncthreads();

#pragma unroll
        for (int ks = 0; ks < 2; ++ks) {
            bf16x8 a[4], b[4];
#pragma unroll
            for (int mf = 0; mf < 4; ++mf) {
                int r  = wm * 64 + mf * 16 + (lane & 15);
                int ch = (ks * 4 + (lane >> 4)) ^ (r & 7);
                a[mf] = *(const bf16x8*)(As + r * 64 + ch * 8);
            }
#pragma unroll
            for (int nf = 0; nf < 4; ++nf) {
                int r  = wn * 64 + nf * 16 + (lane & 15);
                int ch = (ks * 4 + (lane >> 4)) ^ (r & 7);
                b[nf] = *(const bf16x8*)(Bs + r * 64 + ch * 8);
            }
#pragma unroll
            for (int mf = 0; mf < 4; ++mf)
#pragma unroll
                for (int nf = 0; nf < 4; ++nf)
                    acc[mf][nf] = __builtin_amdgcn_mfma_f32_16x16x32_bf16(
                        a[mf], b[nf], acc[mf][nf], 0, 0, 0);
        }
    }

    int rif = (lane >> 4) * 4;
    int col = lane & 15;
#pragma unroll
    for (int mf = 0; mf < 4; ++mf) {
#pragma unroll
        for (int j = 0; j < 4; ++j) {
            int gr = bM + wm * 64 + mf * 16 + rif + j;
#pragma unroll
            for (int nf = 0; nf < 4; ++nf) {
                int gc = bN + wn * 64 + nf * 16 + col;
                out[(size_t)gr * N + gc] = acc[mf][nf][j] + bias[gc];
            }
        }
    }
}

// ---------------------------------------------------------------- logits GEMM
// r2-EXACT structure: 2D grid (N fastest), single LDS buffer, plain
// __syncthreads staging, NO stats epilogue, NO index remap -> VGPR 80,
// 6 waves/SIMD (the proven-fastest config: 221 us). Permuted C write + bias.
__global__ __launch_bounds__(256) void gemm_logits(const unsigned short* __restrict__ A,
                                                   const unsigned short* __restrict__ W,
                                                   const float* __restrict__ bias,
                                                   float* __restrict__ out) {
    __shared__ unsigned short As[128 * 64];
    __shared__ unsigned short Bs[128 * 64];
    const int bM = blockIdx.y * 128;
    const int bN = blockIdx.x * 128;
    const int K = HID;

    int tid  = threadIdx.x;
    int lane = tid & 63;
    int wid  = tid >> 6;
    int wm   = wid >> 1, wn = wid & 1;

    f32x4 acc[4][4];
#pragma unroll
    for (int i = 0; i < 4; ++i)
#pragma unroll
        for (int j = 0; j < 4; ++j) acc[i][j] = (f32x4){0.f, 0.f, 0.f, 0.f};

    int sr[4], sc[4];
#pragma unroll
    for (int q = 0; q < 4; ++q) {
        sr[q] = (wid * 4 + q) * 8 + (lane >> 3);
        sc[q] = (lane & 7) ^ (sr[q] & 7);
    }

    for (int kt = 0; kt < K; kt += 64) {
        __syncthreads();
#pragma unroll
        for (int q = 0; q < 4; ++q) {
            gld_lds16(A + (size_t)(bM + sr[q]) * K + kt + sc[q] * 8, As + (wid * 4 + q) * 512);
            gld_lds16(W + (size_t)(bN + sr[q]) * K + kt + sc[q] * 8, Bs + (wid * 4 + q) * 512);
        }
        __syncthreads();

#pragma unroll
        for (int ks = 0; ks < 2; ++ks) {
            bf16x8 a[4], b[4];
#pragma unroll
            for (int mf = 0; mf < 4; ++mf) {
                int r  = wm * 64 + mf * 16 + (lane & 15);
                int ch = (ks * 4 + (lane >> 4)) ^ (r & 7);
                a[mf] = *(const bf16x8*)(As + r * 64 + ch * 8);
            }
#pragma unroll
            for (int nf = 0; nf < 4; ++nf) {
                int r  = wn * 64 + nf * 16 + (lane & 15);
                int ch = (ks * 4 + (lane >> 4)) ^ (r & 7);
                b[nf] = *(const bf16x8*)(Bs + r * 64 + ch * 8);
            }
#pragma unroll
            for (int mf = 0; mf < 4; ++mf)
#pragma unroll
                for (int nf = 0; nf < 4; ++nf)
                    acc[mf][nf] = __builtin_amdgcn_mfma_f32_16x16x32_bf16(
                        a[mf], b[nf], acc[mf][nf], 0, 0, 0);
        }
    }

    int rif = (lane >> 4) * 4;
    int col = lane & 15;
#pragma unroll
    for (int mf = 0; mf < 4; ++mf) {
#pragma unroll
        for (int j = 0; j < 4; ++j) {
            int gr = bM + wm * 64 + mf * 16 + rif + j;
            int t = gr >> 6, b = gr & 63;
            size_t rowoff = ((size_t)b * T_STEPS + t) * (size_t)VOCABN;
#pragma unroll
            for (int nf = 0; nf < 4; ++nf) {
                int gc = bN + wn * 64 + nf * 16 + col;
                out[rowoff + gc] = acc[mf][nf][j] + bias[gc];
            }
        }
    }
}

// ---------------------------------------------------------------- persistent 30-step GRU (unchanged from r8)
__global__ __launch_bounds__(256, 1) void gru_persistent(
    const unsigned short* __restrict__ h0b,   // [64][1024] bf16
    const float* __restrict__ enc_h,          // [64][1024] fp32
    const unsigned short* __restrict__ Whh,   // [3072][1024] bf16
    const float* __restrict__ b_hh,
    const float* __restrict__ gi,             // [30][64][3072] fp32
    unsigned short* __restrict__ Hall,        // [30][64][1024] bf16
    float* __restrict__ h_final,              // [64][1024] fp32
    unsigned int* __restrict__ flags)         // [64] zeroed per launch
{
    __shared__ unsigned short Wlds[48 * 1024];   // 96 KB
    int tid  = threadIdx.x;
    int lane = tid & 63;
    int wq   = tid >> 6;
    int l15  = lane & 15, l4 = lane >> 4;
    int m0   = blockIdx.x * 16;
    int b    = wq * 16 + l15;
    int mb   = m0 + l4 * 4;

    for (int i = 0; i < 24; ++i) {
        int sb = wq * 24 + i;
        int kt = sb / 3, g = sb % 3;
        const unsigned short* src =
            Whh + (size_t)(g * HID + m0 + l15) * HID + kt * 32 + l4 * 8;
        gld_lds16(src, Wlds + sb * 512);
    }

    float hp[4];
    {
        float4 h4 = *(const float4*)(enc_h + (size_t)b * HID + mb);
        hp[0] = h4.x; hp[1] = h4.y; hp[2] = h4.z; hp[3] = h4.w;
    }
    float bhr[4], bhz[4], bhn[4];
    {
        float4 r4 = *(const float4*)(b_hh + mb);
        float4 z4 = *(const float4*)(b_hh + HID + mb);
        float4 n4 = *(const float4*)(b_hh + 2 * HID + mb);
        bhr[0]=r4.x; bhr[1]=r4.y; bhr[2]=r4.z; bhr[3]=r4.w;
        bhz[0]=z4.x; bhz[1]=z4.y; bhz[2]=z4.z; bhz[3]=z4.w;
        bhn[0]=n4.x; bhn[1]=n4.y; bhn[2]=n4.z; bhn[3]=n4.w;
    }
    __syncthreads();

    int arow16 = b * 128 + l4;

    for (int t = 0; t < T_STEPS; ++t) {
        const float* gib = gi + (size_t)t * BATCH * G3 + (size_t)b * G3;
        float4 giR = *(const float4*)(gib + mb);
        float4 giZ = *(const float4*)(gib + HID + mb);
        float4 giN = *(const float4*)(gib + 2 * HID + mb);
        float gr4[4] = {giR.x, giR.y, giR.z, giR.w};
        float gz4[4] = {giZ.x, giZ.y, giZ.z, giZ.w};
        float gn4[4] = {giN.x, giN.y, giN.z, giN.w};

        if (t > 0) {
            if (tid < 64) {
                while (__hip_atomic_load(flags + tid, __ATOMIC_RELAXED,
                                         __HIP_MEMORY_SCOPE_AGENT) < (unsigned)t) {}
            }
            __builtin_amdgcn_sched_barrier(0);
            __syncthreads();
            asm volatile("" ::: "memory");
        }

        const unsigned short* Asrc = (t == 0) ? h0b : (Hall + (size_t)(t - 1) * BATCH * HID);
        const bf16x8* A16 = (const bf16x8*)Asrc;

        bf16x8 hreg[32];
#pragma unroll
        for (int kt = 0; kt < 32; ++kt) hreg[kt] = A16[arow16 + kt * 4];

        f32x4 acc[3];
#pragma unroll
        for (int g = 0; g < 3; ++g) acc[g] = (f32x4){0.f, 0.f, 0.f, 0.f};

#pragma unroll
        for (int kt = 0; kt < 32; ++kt) {
#pragma unroll
            for (int g = 0; g < 3; ++g) {
                bf16x8 wfrag = *(const bf16x8*)(Wlds + ((size_t)(kt * 3 + g) * 64 + lane) * 8);
                acc[g] = __builtin_amdgcn_mfma_f32_16x16x32_bf16(wfrag, hreg[kt], acc[g], 0, 0, 0);
            }
        }

        unsigned long long pack = 0;
#pragma unroll
        for (int j = 0; j < 4; ++j) {
            float r = 1.f / (1.f + __expf(-(gr4[j] + acc[0][j] + bhr[j])));
            float z = 1.f / (1.f + __expf(-(gz4[j] + acc[1][j] + bhz[j])));
            float e2 = __expf(2.f * (gn4[j] + r * (acc[2][j] + bhn[j])));
            float n = 1.f - 2.f / (e2 + 1.f);   // tanh
            float hnew = (1.f - z) * n + z * hp[j];
            hp[j] = hnew;
            pack |= (unsigned long long)f2bf(hnew) << (16 * j);
        }
        __hip_atomic_store((unsigned long long*)(Hall + (size_t)t * BATCH * HID +
                                                 (size_t)b * HID + mb),
                           pack, __ATOMIC_RELAXED, __HIP_MEMORY_SCOPE_AGENT);
        if (t == T_STEPS - 1) {
            float4 hf = {hp[0], hp[1], hp[2], hp[3]};
            *(float4*)(h_final + (size_t)b * HID + mb) = hf;
        }

        if (t < T_STEPS - 1) {
            __syncthreads();
            if (tid == 0)
                __hip_atomic_store(flags + blockIdx.x, (unsigned)(t + 1),
                                   __ATOMIC_RELAXED, __HIP_MEMORY_SCOPE_AGENT);
        }
    }
}

// ---------------------------------------------------------------- fused log-softmax:
// one block per row. Pass 1: online (max, sumexp) streaming from HBM.
// Pass 2: apply (row re-read hits L2/L3). Replaces lsm_stats + lsm_apply:
// saves one full 246 MB HBM read.
__global__ __launch_bounds__(256) void lsm_fused(float* __restrict__ out) {
    float4* p4 = (float4*)(out + (size_t)blockIdx.x * VOCABN);
    int tid = threadIdx.x;
    int lane = tid & 63, w = tid >> 6;
    __shared__ float2 sred[4];
    __shared__ float sc;

    float m = -1e30f, s = 0.f;
    for (int i = tid; i < VOCABN / 4; i += 256) {
        float4 v = p4[i];
        float cm = fmaxf(fmaxf(v.x, v.y), fmaxf(v.z, v.w));
        if (cm > m) { s *= __expf(m - cm); m = cm; }
        s += __expf(v.x - m) + __expf(v.y - m) + __expf(v.z - m) + __expf(v.w - m);
    }
#pragma unroll
    for (int off = 1; off < 64; off <<= 1) {
        float om = __shfl_xor(m, off, 64);
        float os = __shfl_xor(s, off, 64);
        float nm = fmaxf(m, om);
        s = s * __expf(m - nm) + os * __expf(om - nm);
        m = nm;
    }
    if (lane == 0) sred[w] = make_float2(m, s);
    __syncthreads();
    if (tid == 0) {
        float fm = sred[0].x, fs = sred[0].y;
#pragma unroll
        for (int k = 1; k < 4; ++k) {
            float om = sred[k].x, os = sred[k].y;
            float nm = fmaxf(fm, om);
            fs = fs * __expf(fm - nm) + os * __expf(om - nm);
            fm = nm;
        }
        sc = fm + logf(fs);
    }
    __syncthreads();
    float c = sc;
    for (int i = tid; i < VOCABN / 4; i += 256) {
        float4 v = p4[i];
        v.x -= c; v.y -= c; v.z -= c; v.w -= c;
        p4[i] = v;
    }
}

// ----------------------------------------------------------------
extern "C" void kernel_launch(void* const* d_in, const int* in_sizes, int n_in,
                              void* d_out, int out_size, void* d_ws, size_t ws_size,
                              hipStream_t stream) {
    const float* enc_h  = (const float*)d_in[1];
    const int*   target = (const int*)d_in[2];
    const float* emb    = (const float*)d_in[3];
    const float* w_ih   = (const float*)d_in[4];
    const float* w_hh   = (const float*)d_in[5];
    const float* b_ih   = (const float*)d_in[6];
    const float* b_hh   = (const float*)d_in[7];
    const float* out_w  = (const float*)d_in[8];
    const float* out_b  = (const float*)d_in[9];
    float* out = (float*)d_out;

    char* p = (char*)d_ws;
    unsigned short* Xb   = (unsigned short*)p; p += (size_t)ROWS * HID * 2;
    unsigned short* Wih  = (unsigned short*)p; p += (size_t)G3 * HID * 2;
    unsigned short* OutW = (unsigned short*)p; p += (size_t)VOCABN * HID * 2;
    unsigned short* Hall = (unsigned short*)p; p += (size_t)ROWS * HID * 2;
    float* gi   = (float*)p; p += (size_t)ROWS * G3 * 4;
    unsigned short* Whhb = (unsigned short*)p; p += (size_t)G3 * HID * 2;
    unsigned short* h0b  = (unsigned short*)p; p += (size_t)BATCH * HID * 2;
    unsigned int* bar = (unsigned int*)p; p += 64 * sizeof(unsigned int);

    f32_to_bf16<<<768, 256, 0, stream>>>(w_ih, Wih, G3 * HID / 4);
    f32_to_bf16<<<768, 256, 0, stream>>>(w_hh, Whhb, G3 * HID / 4);
    f32_to_bf16<<<2048, 256, 0, stream>>>(out_w, OutW, VOCABN * HID / 4);
    f32_to_bf16<<<64, 256, 0, stream>>>(enc_h, h0b, BATCH * HID / 4);
    embed_relu_bf16<<<ROWS, 256, 0, stream>>>(target, emb, Xb);
    init_bar<<<1, 64, 0, stream>>>(bar);

    gemm_mfma_bt<<<dim3(G3 / 128, ROWS / 128), 256, 0, stream>>>(Xb, Wih, b_ih, gi, G3, HID);

    {
        const unsigned short* a0 = h0b;
        const float* a1 = enc_h;
        const unsigned short* a2 = Whhb;
        const float* a3 = b_hh;
        const float* a4 = gi;
        unsigned short* a5 = Hall;
        float* a6 = out + OUT_HID_OFF;
        unsigned int* a7 = bar;
        void* args[] = {&a0, &a1, &a2, &a3, &a4, &a5, &a6, &a7};
        hipLaunchCooperativeKernel((void*)gru_persistent, dim3(64), dim3(256),
                                   args, 0, stream);
    }

    gemm_logits<<<dim3(NBX, NBY), 256, 0, stream>>>(Hall, OutW, out_b, out);
    lsm_fused<<<ROWS, 256, 0, stream>>>(out);
}

// Round 14
// 596.160 us; speedup vs baseline: 1.0466x; 1.0112x over previous
//
#include <hip/hip_runtime.h>
#include <math.h>

#define T_STEPS 30
#define BATCH   64
#define HID     1024
#define VOCABN  32000
#define G3      3072
#define ROWS    (T_STEPS * BATCH)   // 1920
#define ROWS_PAD 2048
#define OUT_HID_OFF ((size_t)BATCH * T_STEPS * VOCABN)  // 61,440,000

typedef __attribute__((ext_vector_type(8))) short bf16x8;
typedef __attribute__((ext_vector_type(4))) float f32x4;

__device__ __forceinline__ unsigned short f2bf(float f) {
    union { float f; unsigned u; } x; x.f = f;
    unsigned r = x.u + 0x7fffu + ((x.u >> 16) & 1u);
    return (unsigned short)(r >> 16);
}

__device__ __forceinline__ void gld_lds16(const unsigned short* g, unsigned short* l) {
    __builtin_amdgcn_global_load_lds(
        (const __attribute__((address_space(1))) unsigned*)g,
        (__attribute__((address_space(3))) unsigned*)l, 16, 0, 0);
}

// ---------------------------------------------------------------- fp32 -> bf16 (RNE)
__global__ __launch_bounds__(256) void f32_to_bf16(const float* __restrict__ src,
                                                   unsigned short* __restrict__ dst, int n4) {
    int i = blockIdx.x * 256 + threadIdx.x;
    int stride = gridDim.x * 256;
    for (; i < n4; i += stride) {
        float4 v = ((const float4*)src)[i];
        ushort4 o;
        o.x = f2bf(v.x); o.y = f2bf(v.y); o.z = f2bf(v.z); o.w = f2bf(v.w);
        ((ushort4*)dst)[i] = o;
    }
}

// ---------------------------------------------------------------- X = relu(emb[tok]) -> bf16
__global__ __launch_bounds__(256) void embed_relu_bf16(const int* __restrict__ target,
                                                       const float* __restrict__ emb,
                                                       unsigned short* __restrict__ X) {
    int bid = blockIdx.x;           // t*64 + b
    int t = bid >> 6, b = bid & 63;
    int tok = (t == 0) ? 0 : target[b * T_STEPS + (t - 1)];
    const float4* src = (const float4*)(emb + (size_t)tok * HID);
    float4 v = src[threadIdx.x];
    ushort4 o;
    o.x = f2bf(fmaxf(v.x, 0.f)); o.y = f2bf(fmaxf(v.y, 0.f));
    o.z = f2bf(fmaxf(v.z, 0.f)); o.w = f2bf(fmaxf(v.w, 0.f));
    ((ushort4*)(X + (size_t)bid * HID))[threadIdx.x] = o;
}

// ---------------------------------------------------------------- barrier flags init (64 flags)
__global__ void init_bar(unsigned int* bar) {
    if (threadIdx.x < 64) bar[threadIdx.x] = 0u;
}

// ---------------------------------------------------------------- gi GEMM (unchanged 128^2)
__global__ __launch_bounds__(256) void gemm_mfma_bt(const unsigned short* __restrict__ A,
                                                    const unsigned short* __restrict__ W,
                                                    const float* __restrict__ bias,
                                                    float* __restrict__ out,
                                                    int N, int K) {
    __shared__ unsigned short As[128 * 64];
    __shared__ unsigned short Bs[128 * 64];
    int tid  = threadIdx.x;
    int lane = tid & 63;
    int wid  = tid >> 6;
    int wm   = wid >> 1, wn = wid & 1;
    const int bM = blockIdx.y * 128;
    const int bN = blockIdx.x * 128;

    f32x4 acc[4][4];
#pragma unroll
    for (int i = 0; i < 4; ++i)
#pragma unroll
        for (int j = 0; j < 4; ++j) acc[i][j] = (f32x4){0.f, 0.f, 0.f, 0.f};

    int sr[4], sc[4];
#pragma unroll
    for (int q = 0; q < 4; ++q) {
        sr[q] = (wid * 4 + q) * 8 + (lane >> 3);
        sc[q] = (lane & 7) ^ (sr[q] & 7);
    }

    for (int kt = 0; kt < K; kt += 64) {
        __syncthreads();
#pragma unroll
        for (int q = 0; q < 4; ++q) {
            gld_lds16(A + (size_t)(bM + sr[q]) * K + kt + sc[q] * 8, As + (wid * 4 + q) * 512);
            gld_lds16(W + (size_t)(bN + sr[q]) * K + kt + sc[q] * 8, Bs + (wid * 4 + q) * 512);
        }
        __syncthreads();

#pragma unroll
        for (int ks = 0; ks < 2; ++ks) {
            bf16x8 a[4], b[4];
#pragma unroll
            for (int mf = 0; mf < 4; ++mf) {
                int r  = wm * 64 + mf * 16 + (lane & 15);
                int ch = (ks * 4 + (lane >> 4)) ^ (r & 7);
                a[mf] = *(const bf16x8*)(As + r * 64 + ch * 8);
            }
#pragma unroll
            for (int nf = 0; nf < 4; ++nf) {
                int r  = wn * 64 + nf * 16 + (lane & 15);
                int ch = (ks * 4 + (lane >> 4)) ^ (r & 7);
                b[nf] = *(const bf16x8*)(Bs + r * 64 + ch * 8);
            }
#pragma unroll
            for (int mf = 0; mf < 4; ++mf)
#pragma unroll
                for (int nf = 0; nf < 4; ++nf)
                    acc[mf][nf] = __builtin_amdgcn_mfma_f32_16x16x32_bf16(
                        a[mf], b[nf], acc[mf][nf], 0, 0, 0);
        }
    }

    int rif = (lane >> 4) * 4;
    int col = lane & 15;
#pragma unroll
    for (int mf = 0; mf < 4; ++mf) {
#pragma unroll
        for (int j = 0; j < 4; ++j) {
            int gr = bM + wm * 64 + mf * 16 + rif + j;
#pragma unroll
            for (int nf = 0; nf < 4; ++nf) {
                int gc = bN + wn * 64 + nf * 16 + col;
                out[(size_t)gr * N + gc] = acc[mf][nf][j] + bias[gc];
            }
        }
    }
}

// ---------------------------------------------------------------- logits GEMM: 256^2 tile,
// 8 waves (2Mx4N), K as 32 sub-tiles of 32, 4-deep LDS ring, counted vmcnt(8)
// (never drained in-loop), raw s_barrier, setprio around MFMA cluster.
// Swizzle: both-sides XOR involution ch ^= (r>>1)&3 on 16B chunks of 64B rows.
// M padded to 2048 (A rows 1920..2047 garbage, C-writes guarded).
__global__ __launch_bounds__(512) void gemm_logits256(const unsigned short* __restrict__ A,
                                                      const unsigned short* __restrict__ W,
                                                      const float* __restrict__ bias,
                                                      float* __restrict__ out) {
    __shared__ unsigned short As[4][256 * 32];   // 16 KB per slot
    __shared__ unsigned short Bs[4][256 * 32];
    const int bM = blockIdx.x * 256;   // M fastest: 8 consecutive blocks share one OutW panel
    const int bN = blockIdx.y * 256;

    int tid  = threadIdx.x;
    int lane = tid & 63;
    int wid  = tid >> 6;         // 0..7
    int wm   = wid >> 2;         // 0..1 -> 128 M-rows
    int wn   = wid & 3;          // 0..3 -> 64 N-cols
    int l15  = lane & 15, l4 = lane >> 4;

    // staging geometry: sub-tile = 256 rows x 32 K (1024 chunks of 16B);
    // wave wid covers chunks [wid*128, +128) via 2 issues of 64 chunks.
    size_t pA[2], pB[2];
    int ldst[2];
#pragma unroll
    for (int i = 0; i < 2; ++i) {
        int c = wid * 128 + i * 64 + lane;
        int r = c >> 2, cc = c & 3;
        int so = (cc ^ ((r >> 1) & 3)) * 8;        // pre-swizzled source chunk
        pA[i] = (size_t)(bM + r) * HID + so;
        pB[i] = (size_t)(bN + r) * HID + so;
        ldst[i] = wid * 1024 + i * 512;            // linear LDS dest (ushorts)
    }

    f32x4 acc[8][4];
#pragma unroll
    for (int i = 0; i < 8; ++i)
#pragma unroll
        for (int j = 0; j < 4; ++j) acc[i][j] = (f32x4){0.f, 0.f, 0.f, 0.f};

    // fragment read offsets (ushort units); swizzle term (l15>>1)&3 is mf/nf-invariant
    int chsw = (l4 ^ ((l15 >> 1) & 3)) * 8;
    int aoff[8], boff[4];
#pragma unroll
    for (int mf = 0; mf < 8; ++mf) aoff[mf] = (wm * 128 + mf * 16 + l15) * 32 + chsw;
#pragma unroll
    for (int nf = 0; nf < 4; ++nf) boff[nf] = (wn * 64 + nf * 16 + l15) * 32 + chsw;

    auto issue = [&](int s) {
        int slot = s & 3;
#pragma unroll
        for (int i = 0; i < 2; ++i)
            gld_lds16(A + pA[i] + s * 32, &As[slot][ldst[i]]);
#pragma unroll
        for (int i = 0; i < 2; ++i)
            gld_lds16(W + pB[i] + s * 32, &Bs[slot][ldst[i]]);
    };

    issue(0); issue(1); issue(2);   // 12 vmem instrs in flight per wave

#pragma unroll 1
    for (int s = 0; s < 32; ++s) {
        // own sub-tile-s loads landed; keep s+1, s+2 in flight (8 instrs)
        if (s < 30)       asm volatile("s_waitcnt vmcnt(8)" ::: "memory");
        else if (s == 30) asm volatile("s_waitcnt vmcnt(4)" ::: "memory");
        else              asm volatile("s_waitcnt vmcnt(0)" ::: "memory");
        __builtin_amdgcn_s_barrier();      // all waves: sub-tile s landed, s-1 reads done
        asm volatile("" ::: "memory");     // no IR load motion above the barrier
        __builtin_amdgcn_sched_barrier(0);
        if (s < 29) issue(s + 3);          // overwrites slot (s-1)&3 -- safe after barrier

        int slot = s & 3;
        const unsigned short* ab = As[slot];
        const unsigned short* bb = Bs[slot];
        bf16x8 a[8], b[4];
#pragma unroll
        for (int mf = 0; mf < 8; ++mf) a[mf] = *(const bf16x8*)(ab + aoff[mf]);
#pragma unroll
        for (int nf = 0; nf < 4; ++nf) b[nf] = *(const bf16x8*)(bb + boff[nf]);
        __builtin_amdgcn_s_setprio(1);
#pragma unroll
        for (int mf = 0; mf < 8; ++mf)
#pragma unroll
            for (int nf = 0; nf < 4; ++nf)
                acc[mf][nf] = __builtin_amdgcn_mfma_f32_16x16x32_bf16(
                    a[mf], b[nf], acc[mf][nf], 0, 0, 0);
        __builtin_amdgcn_s_setprio(0);
    }

    // epilogue: permuted row write + bias, guarded for pad rows
    int col = l15;
    float b4[4];
#pragma unroll
    for (int nf = 0; nf < 4; ++nf) b4[nf] = bias[bN + wn * 64 + nf * 16 + col];
    int rif = l4 * 4;
#pragma unroll
    for (int mf = 0; mf < 8; ++mf) {
#pragma unroll
        for (int j = 0; j < 4; ++j) {
            int gr = bM + wm * 128 + mf * 16 + rif + j;
            if (gr < ROWS) {
                int t = gr >> 6, b_ = gr & 63;
                size_t rowoff = ((size_t)b_ * T_STEPS + t) * (size_t)VOCABN;
#pragma unroll
                for (int nf = 0; nf < 4; ++nf)
                    out[rowoff + bN + wn * 64 + nf * 16 + col] = acc[mf][nf][j] + b4[nf];
            }
        }
    }
}

// ---------------------------------------------------------------- persistent 30-step GRU (unchanged from r8)
__global__ __launch_bounds__(256, 1) void gru_persistent(
    const unsigned short* __restrict__ h0b,   // [64][1024] bf16
    const float* __restrict__ enc_h,          // [64][1024] fp32
    const unsigned short* __restrict__ Whh,   // [3072][1024] bf16
    const float* __restrict__ b_hh,
    const float* __restrict__ gi,             // [30][64][3072] fp32
    unsigned short* __restrict__ Hall,        // [30][64][1024] bf16 (buffer padded to 2048 rows)
    float* __restrict__ h_final,              // [64][1024] fp32
    unsigned int* __restrict__ flags)         // [64] zeroed per launch
{
    __shared__ unsigned short Wlds[48 * 1024];   // 96 KB
    int tid  = threadIdx.x;
    int lane = tid & 63;
    int wq   = tid >> 6;
    int l15  = lane & 15, l4 = lane >> 4;
    int m0   = blockIdx.x * 16;
    int b    = wq * 16 + l15;
    int mb   = m0 + l4 * 4;

    for (int i = 0; i < 24; ++i) {
        int sb = wq * 24 + i;
        int kt = sb / 3, g = sb % 3;
        const unsigned short* src =
            Whh + (size_t)(g * HID + m0 + l15) * HID + kt * 32 + l4 * 8;
        gld_lds16(src, Wlds + sb * 512);
    }

    float hp[4];
    {
        float4 h4 = *(const float4*)(enc_h + (size_t)b * HID + mb);
        hp[0] = h4.x; hp[1] = h4.y; hp[2] = h4.z; hp[3] = h4.w;
    }
    float bhr[4], bhz[4], bhn[4];
    {
        float4 r4 = *(const float4*)(b_hh + mb);
        float4 z4 = *(const float4*)(b_hh + HID + mb);
        float4 n4 = *(const float4*)(b_hh + 2 * HID + mb);
        bhr[0]=r4.x; bhr[1]=r4.y; bhr[2]=r4.z; bhr[3]=r4.w;
        bhz[0]=z4.x; bhz[1]=z4.y; bhz[2]=z4.z; bhz[3]=z4.w;
        bhn[0]=n4.x; bhn[1]=n4.y; bhn[2]=n4.z; bhn[3]=n4.w;
    }
    __syncthreads();

    int arow16 = b * 128 + l4;

    for (int t = 0; t < T_STEPS; ++t) {
        const float* gib = gi + (size_t)t * BATCH * G3 + (size_t)b * G3;
        float4 giR = *(const float4*)(gib + mb);
        float4 giZ = *(const float4*)(gib + HID + mb);
        float4 giN = *(const float4*)(gib + 2 * HID + mb);
        float gr4[4] = {giR.x, giR.y, giR.z, giR.w};
        float gz4[4] = {giZ.x, giZ.y, giZ.z, giZ.w};
        float gn4[4] = {giN.x, giN.y, giN.z, giN.w};

        if (t > 0) {
            if (tid < 64) {
                while (__hip_atomic_load(flags + tid, __ATOMIC_RELAXED,
                                         __HIP_MEMORY_SCOPE_AGENT) < (unsigned)t) {}
            }
            __builtin_amdgcn_sched_barrier(0);
            __syncthreads();
            asm volatile("" ::: "memory");
        }

        const unsigned short* Asrc = (t == 0) ? h0b : (Hall + (size_t)(t - 1) * BATCH * HID);
        const bf16x8* A16 = (const bf16x8*)Asrc;

        bf16x8 hreg[32];
#pragma unroll
        for (int kt = 0; kt < 32; ++kt) hreg[kt] = A16[arow16 + kt * 4];

        f32x4 acc[3];
#pragma unroll
        for (int g = 0; g < 3; ++g) acc[g] = (f32x4){0.f, 0.f, 0.f, 0.f};

#pragma unroll
        for (int kt = 0; kt < 32; ++kt) {
#pragma unroll
            for (int g = 0; g < 3; ++g) {
                bf16x8 wfrag = *(const bf16x8*)(Wlds + ((size_t)(kt * 3 + g) * 64 + lane) * 8);
                acc[g] = __builtin_amdgcn_mfma_f32_16x16x32_bf16(wfrag, hreg[kt], acc[g], 0, 0, 0);
            }
        }

        unsigned long long pack = 0;
#pragma unroll
        for (int j = 0; j < 4; ++j) {
            float r = 1.f / (1.f + __expf(-(gr4[j] + acc[0][j] + bhr[j])));
            float z = 1.f / (1.f + __expf(-(gz4[j] + acc[1][j] + bhz[j])));
            float e2 = __expf(2.f * (gn4[j] + r * (acc[2][j] + bhn[j])));
            float n = 1.f - 2.f / (e2 + 1.f);   // tanh
            float hnew = (1.f - z) * n + z * hp[j];
            hp[j] = hnew;
            pack |= (unsigned long long)f2bf(hnew) << (16 * j);
        }
        __hip_atomic_store((unsigned long long*)(Hall + (size_t)t * BATCH * HID +
                                                 (size_t)b * HID + mb),
                           pack, __ATOMIC_RELAXED, __HIP_MEMORY_SCOPE_AGENT);
        if (t == T_STEPS - 1) {
            float4 hf = {hp[0], hp[1], hp[2], hp[3]};
            *(float4*)(h_final + (size_t)b * HID + mb) = hf;
        }

        if (t < T_STEPS - 1) {
            __syncthreads();
            if (tid == 0)
                __hip_atomic_store(flags + blockIdx.x, (unsigned)(t + 1),
                                   __ATOMIC_RELAXED, __HIP_MEMORY_SCOPE_AGENT);
        }
    }
}

// ---------------------------------------------------------------- fused log-softmax (unchanged)
__global__ __launch_bounds__(256) void lsm_fused(float* __restrict__ out) {
    float4* p4 = (float4*)(out + (size_t)blockIdx.x * VOCABN);
    int tid = threadIdx.x;
    int lane = tid & 63, w = tid >> 6;
    __shared__ float2 sred[4];
    __shared__ float sc;

    float m = -1e30f, s = 0.f;
    for (int i = tid; i < VOCABN / 4; i += 256) {
        float4 v = p4[i];
        float cm = fmaxf(fmaxf(v.x, v.y), fmaxf(v.z, v.w));
        if (cm > m) { s *= __expf(m - cm); m = cm; }
        s += __expf(v.x - m) + __expf(v.y - m) + __expf(v.z - m) + __expf(v.w - m);
    }
#pragma unroll
    for (int off = 1; off < 64; off <<= 1) {
        float om = __shfl_xor(m, off, 64);
        float os = __shfl_xor(s, off, 64);
        float nm = fmaxf(m, om);
        s = s * __expf(m - nm) + os * __expf(om - nm);
        m = nm;
    }
    if (lane == 0) sred[w] = make_float2(m, s);
    __syncthreads();
    if (tid == 0) {
        float fm = sred[0].x, fs = sred[0].y;
#pragma unroll
        for (int k = 1; k < 4; ++k) {
            float om = sred[k].x, os = sred[k].y;
            float nm = fmaxf(fm, om);
            fs = fs * __expf(fm - nm) + os * __expf(om - nm);
            fm = nm;
        }
        sc = fm + logf(fs);
    }
    __syncthreads();
    float c = sc;
    for (int i = tid; i < VOCABN / 4; i += 256) {
        float4 v = p4[i];
        v.x -= c; v.y -= c; v.z -= c; v.w -= c;
        p4[i] = v;
    }
}

// ----------------------------------------------------------------
extern "C" void kernel_launch(void* const* d_in, const int* in_sizes, int n_in,
                              void* d_out, int out_size, void* d_ws, size_t ws_size,
                              hipStream_t stream) {
    const float* enc_h  = (const float*)d_in[1];
    const int*   target = (const int*)d_in[2];
    const float* emb    = (const float*)d_in[3];
    const float* w_ih   = (const float*)d_in[4];
    const float* w_hh   = (const float*)d_in[5];
    const float* b_ih   = (const float*)d_in[6];
    const float* b_hh   = (const float*)d_in[7];
    const float* out_w  = (const float*)d_in[8];
    const float* out_b  = (const float*)d_in[9];
    float* out = (float*)d_out;

    char* p = (char*)d_ws;
    unsigned short* Xb   = (unsigned short*)p; p += (size_t)ROWS * HID * 2;
    unsigned short* Wih  = (unsigned short*)p; p += (size_t)G3 * HID * 2;
    unsigned short* OutW = (unsigned short*)p; p += (size_t)VOCABN * HID * 2;
    unsigned short* Hall = (unsigned short*)p; p += (size_t)ROWS_PAD * HID * 2;  // padded to 2048 rows
    float* gi   = (float*)p; p += (size_t)ROWS * G3 * 4;
    unsigned short* Whhb = (unsigned short*)p; p += (size_t)G3 * HID * 2;
    unsigned short* h0b  = (unsigned short*)p; p += (size_t)BATCH * HID * 2;
    unsigned int* bar = (unsigned int*)p; p += 64 * sizeof(unsigned int);

    f32_to_bf16<<<768, 256, 0, stream>>>(w_ih, Wih, G3 * HID / 4);
    f32_to_bf16<<<768, 256, 0, stream>>>(w_hh, Whhb, G3 * HID / 4);
    f32_to_bf16<<<2048, 256, 0, stream>>>(out_w, OutW, VOCABN * HID / 4);
    f32_to_bf16<<<64, 256, 0, stream>>>(enc_h, h0b, BATCH * HID / 4);
    embed_relu_bf16<<<ROWS, 256, 0, stream>>>(target, emb, Xb);
    init_bar<<<1, 64, 0, stream>>>(bar);

    gemm_mfma_bt<<<dim3(G3 / 128, ROWS / 128), 256, 0, stream>>>(Xb, Wih, b_ih, gi, G3, HID);

    {
        const unsigned short* a0 = h0b;
        const float* a1 = enc_h;
        const unsigned short* a2 = Whhb;
        const float* a3 = b_hh;
        const float* a4 = gi;
        unsigned short* a5 = Hall;
        float* a6 = out + OUT_HID_OFF;
        unsigned int* a7 = bar;
        void* args[] = {&a0, &a1, &a2, &a3, &a4, &a5, &a6, &a7};
        hipLaunchCooperativeKernel((void*)gru_persistent, dim3(64), dim3(256),
                                   args, 0, stream);
    }

    gemm_logits256<<<dim3(ROWS_PAD / 256, VOCABN / 256), 512, 0, stream>>>(Hall, OutW, out_b, out);
    lsm_fused<<<ROWS, 256, 0, stream>>>(out);
}

// Round 15
// 550.956 us; speedup vs baseline: 1.1324x; 1.0820x over previous
//
#include <hip/hip_runtime.h>
#include <math.h>

#define T_STEPS 30
#define BATCH   64
#define HID     1024
#define VOCABN  32000
#define G3      3072
#define ROWS    (T_STEPS * BATCH)   // 1920
#define ROWS_PAD 2048
#define OUT_HID_OFF ((size_t)BATCH * T_STEPS * VOCABN)  // 61,440,000
#define NPART 500                   // 125 panels x 4 wn-segments

typedef __attribute__((ext_vector_type(8))) short bf16x8;
typedef __attribute__((ext_vector_type(4))) float f32x4;

__device__ __forceinline__ unsigned short f2bf(float f) {
    union { float f; unsigned u; } x; x.f = f;
    unsigned r = x.u + 0x7fffu + ((x.u >> 16) & 1u);
    return (unsigned short)(r >> 16);
}

__device__ __forceinline__ void gld_lds16(const unsigned short* g, unsigned short* l) {
    __builtin_amdgcn_global_load_lds(
        (const __attribute__((address_space(1))) unsigned*)g,
        (__attribute__((address_space(3))) unsigned*)l, 16, 0, 0);
}

// ---------------------------------------------------------------- fp32 -> bf16 (RNE)
__global__ __launch_bounds__(256) void f32_to_bf16(const float* __restrict__ src,
                                                   unsigned short* __restrict__ dst, int n4) {
    int i = blockIdx.x * 256 + threadIdx.x;
    int stride = gridDim.x * 256;
    for (; i < n4; i += stride) {
        float4 v = ((const float4*)src)[i];
        ushort4 o;
        o.x = f2bf(v.x); o.y = f2bf(v.y); o.z = f2bf(v.z); o.w = f2bf(v.w);
        ((ushort4*)dst)[i] = o;
    }
}

// ---------------------------------------------------------------- X = relu(emb[tok]) -> bf16
__global__ __launch_bounds__(256) void embed_relu_bf16(const int* __restrict__ target,
                                                       const float* __restrict__ emb,
                                                       unsigned short* __restrict__ X) {
    int bid = blockIdx.x;           // t*64 + b
    int t = bid >> 6, b = bid & 63;
    int tok = (t == 0) ? 0 : target[b * T_STEPS + (t - 1)];
    const float4* src = (const float4*)(emb + (size_t)tok * HID);
    float4 v = src[threadIdx.x];
    ushort4 o;
    o.x = f2bf(fmaxf(v.x, 0.f)); o.y = f2bf(fmaxf(v.y, 0.f));
    o.z = f2bf(fmaxf(v.z, 0.f)); o.w = f2bf(fmaxf(v.w, 0.f));
    ((ushort4*)(X + (size_t)bid * HID))[threadIdx.x] = o;
}

// ---------------------------------------------------------------- barrier flags init (64 flags)
__global__ void init_bar(unsigned int* bar) {
    if (threadIdx.x < 64) bar[threadIdx.x] = 0u;
}

// ---------------------------------------------------------------- gi GEMM (unchanged 128^2)
__global__ __launch_bounds__(256) void gemm_mfma_bt(const unsigned short* __restrict__ A,
                                                    const unsigned short* __restrict__ W,
                                                    const float* __restrict__ bias,
                                                    float* __restrict__ out,
                                                    int N, int K) {
    __shared__ unsigned short As[128 * 64];
    __shared__ unsigned short Bs[128 * 64];
    int tid  = threadIdx.x;
    int lane = tid & 63;
    int wid  = tid >> 6;
    int wm   = wid >> 1, wn = wid & 1;
    const int bM = blockIdx.y * 128;
    const int bN = blockIdx.x * 128;

    f32x4 acc[4][4];
#pragma unroll
    for (int i = 0; i < 4; ++i)
#pragma unroll
        for (int j = 0; j < 4; ++j) acc[i][j] = (f32x4){0.f, 0.f, 0.f, 0.f};

    int sr[4], sc[4];
#pragma unroll
    for (int q = 0; q < 4; ++q) {
        sr[q] = (wid * 4 + q) * 8 + (lane >> 3);
        sc[q] = (lane & 7) ^ (sr[q] & 7);
    }

    for (int kt = 0; kt < K; kt += 64) {
        __syncthreads();
#pragma unroll
        for (int q = 0; q < 4; ++q) {
            gld_lds16(A + (size_t)(bM + sr[q]) * K + kt + sc[q] * 8, As + (wid * 4 + q) * 512);
            gld_lds16(W + (size_t)(bN + sr[q]) * K + kt + sc[q] * 8, Bs + (wid * 4 + q) * 512);
        }
        __syncthreads();

#pragma unroll
        for (int ks = 0; ks < 2; ++ks) {
            bf16x8 a[4], b[4];
#pragma unroll
            for (int mf = 0; mf < 4; ++mf) {
                int r  = wm * 64 + mf * 16 + (lane & 15);
                int ch = (ks * 4 + (lane >> 4)) ^ (r & 7);
                a[mf] = *(const bf16x8*)(As + r * 64 + ch * 8);
            }
#pragma unroll
            for (int nf = 0; nf < 4; ++nf) {
                int r  = wn * 64 + nf * 16 + (lane & 15);
                int ch = (ks * 4 + (lane >> 4)) ^ (r & 7);
                b[nf] = *(const bf16x8*)(Bs + r * 64 + ch * 8);
            }
#pragma unroll
            for (int mf = 0; mf < 4; ++mf)
#pragma unroll
                for (int nf = 0; nf < 4; ++nf)
                    acc[mf][nf] = __builtin_amdgcn_mfma_f32_16x16x32_bf16(
                        a[mf], b[nf], acc[mf][nf], 0, 0, 0);
        }
    }

    int rif = (lane >> 4) * 4;
    int col = lane & 15;
#pragma unroll
    for (int mf = 0; mf < 4; ++mf) {
#pragma unroll
        for (int j = 0; j < 4; ++j) {
            int gr = bM + wm * 64 + mf * 16 + rif + j;
#pragma unroll
            for (int nf = 0; nf < 4; ++nf) {
                int gc = bN + wn * 64 + nf * 16 + col;
                out[(size_t)gr * N + gc] = acc[mf][nf][j] + bias[gc];
            }
        }
    }
}

// ---------------------------------------------------------------- logits GEMM: 256^2 tile,
// r14 ring pipeline (unchanged loop) + stats epilogue (free: LDS-bound at
// 1 block/CU, so extra VGPR/LDS cost no occupancy). pstatT[part][gr] coalesced.
__global__ __launch_bounds__(512) void gemm_logits256(const unsigned short* __restrict__ A,
                                                      const unsigned short* __restrict__ W,
                                                      const float* __restrict__ bias,
                                                      float* __restrict__ out,
                                                      float2* __restrict__ pstatT) {
    __shared__ unsigned short As[4][256 * 32];   // 16 KB per slot
    __shared__ unsigned short Bs[4][256 * 32];
    __shared__ float2 sstat[8][128];             // 8 KB
    const int bM = blockIdx.x * 256;
    const int bN = blockIdx.y * 256;

    int tid  = threadIdx.x;
    int lane = tid & 63;
    int wid  = tid >> 6;         // 0..7
    int wm   = wid >> 2;         // 0..1 -> 128 M-rows
    int wn   = wid & 3;          // 0..3 -> 64 N-cols
    int l15  = lane & 15, l4 = lane >> 4;

    size_t pA[2], pB[2];
    int ldst[2];
#pragma unroll
    for (int i = 0; i < 2; ++i) {
        int c = wid * 128 + i * 64 + lane;
        int r = c >> 2, cc = c & 3;
        int so = (cc ^ ((r >> 1) & 3)) * 8;
        pA[i] = (size_t)(bM + r) * HID + so;
        pB[i] = (size_t)(bN + r) * HID + so;
        ldst[i] = wid * 1024 + i * 512;
    }

    f32x4 acc[8][4];
#pragma unroll
    for (int i = 0; i < 8; ++i)
#pragma unroll
        for (int j = 0; j < 4; ++j) acc[i][j] = (f32x4){0.f, 0.f, 0.f, 0.f};

    int chsw = (l4 ^ ((l15 >> 1) & 3)) * 8;
    int aoff[8], boff[4];
#pragma unroll
    for (int mf = 0; mf < 8; ++mf) aoff[mf] = (wm * 128 + mf * 16 + l15) * 32 + chsw;
#pragma unroll
    for (int nf = 0; nf < 4; ++nf) boff[nf] = (wn * 64 + nf * 16 + l15) * 32 + chsw;

    auto issue = [&](int s) {
        int slot = s & 3;
#pragma unroll
        for (int i = 0; i < 2; ++i)
            gld_lds16(A + pA[i] + s * 32, &As[slot][ldst[i]]);
#pragma unroll
        for (int i = 0; i < 2; ++i)
            gld_lds16(W + pB[i] + s * 32, &Bs[slot][ldst[i]]);
    };

    issue(0); issue(1); issue(2);

#pragma unroll 1
    for (int s = 0; s < 32; ++s) {
        if (s < 30)       asm volatile("s_waitcnt vmcnt(8)" ::: "memory");
        else if (s == 30) asm volatile("s_waitcnt vmcnt(4)" ::: "memory");
        else              asm volatile("s_waitcnt vmcnt(0)" ::: "memory");
        __builtin_amdgcn_s_barrier();
        asm volatile("" ::: "memory");
        __builtin_amdgcn_sched_barrier(0);
        if (s < 29) issue(s + 3);

        int slot = s & 3;
        const unsigned short* ab = As[slot];
        const unsigned short* bb = Bs[slot];
        bf16x8 a[8], b[4];
#pragma unroll
        for (int mf = 0; mf < 8; ++mf) a[mf] = *(const bf16x8*)(ab + aoff[mf]);
#pragma unroll
        for (int nf = 0; nf < 4; ++nf) b[nf] = *(const bf16x8*)(bb + boff[nf]);
        __builtin_amdgcn_s_setprio(1);
#pragma unroll
        for (int mf = 0; mf < 8; ++mf)
#pragma unroll
            for (int nf = 0; nf < 4; ++nf)
                acc[mf][nf] = __builtin_amdgcn_mfma_f32_16x16x32_bf16(
                    a[mf], b[nf], acc[mf][nf], 0, 0, 0);
        __builtin_amdgcn_s_setprio(0);
    }

    // epilogue: permuted C write + bias + per-row-segment (max, sumexp) stats
    int col = l15;
    float b4[4];
#pragma unroll
    for (int nf = 0; nf < 4; ++nf) b4[nf] = bias[bN + wn * 64 + nf * 16 + col];
    int rif = l4 * 4;
#pragma unroll
    for (int mf = 0; mf < 8; ++mf) {
#pragma unroll
        for (int j = 0; j < 4; ++j) {
            int gr = bM + wm * 128 + mf * 16 + rif + j;
            float v[4];
            float mx = -1e30f;
#pragma unroll
            for (int nf = 0; nf < 4; ++nf) {
                v[nf] = acc[mf][nf][j] + b4[nf];
                mx = fmaxf(mx, v[nf]);
            }
            if (gr < ROWS) {
                int t = gr >> 6, b_ = gr & 63;
                size_t rowoff = ((size_t)b_ * T_STEPS + t) * (size_t)VOCABN;
#pragma unroll
                for (int nf = 0; nf < 4; ++nf)
                    out[rowoff + bN + wn * 64 + nf * 16 + col] = v[nf];
            }
#pragma unroll
            for (int off = 1; off < 16; off <<= 1) mx = fmaxf(mx, __shfl_xor(mx, off, 64));
            float se = 0.f;
#pragma unroll
            for (int nf = 0; nf < 4; ++nf) se += __expf(v[nf] - mx);
#pragma unroll
            for (int off = 1; off < 16; off <<= 1) se += __shfl_xor(se, off, 64);
            if (l15 == 0) sstat[wid][mf * 16 + rif + j] = make_float2(mx, se);
        }
    }
    __syncthreads();
    for (int i = tid; i < 1024; i += 512) {
        int ws_ = i >> 7, rl = i & 127;
        int gr = bM + (ws_ >> 2) * 128 + rl;
        if (gr < ROWS)
            pstatT[(size_t)(blockIdx.y * 4 + (ws_ & 3)) * ROWS + gr] = sstat[ws_][rl];
    }
}

// ---------------------------------------------------------------- persistent 30-step GRU
// Grid 256 (cooperative): blocks 0-63 = recurrence (unchanged r8 logic);
// blocks 64-255 = OutW f32->bf16 convert (196 MB, hidden under the ~170 us
// recurrence on otherwise-idle CUs), then exit.
__global__ __launch_bounds__(256, 1) void gru_persistent(
    const unsigned short* __restrict__ h0b,   // [64][1024] bf16
    const float* __restrict__ enc_h,          // [64][1024] fp32
    const unsigned short* __restrict__ Whh,   // [3072][1024] bf16
    const float* __restrict__ b_hh,
    const float* __restrict__ gi,             // [30][64][3072] fp32
    unsigned short* __restrict__ Hall,        // [30][64][1024] bf16 (2048-row buffer)
    float* __restrict__ h_final,              // [64][1024] fp32
    unsigned int* __restrict__ flags,         // [64] zeroed per launch
    const float* __restrict__ outw_f32,       // [32000*1024] fp32
    unsigned short* __restrict__ outw_bf)     // [32000*1024] bf16
{
    __shared__ unsigned short Wlds[48 * 1024];   // 96 KB
    int tid  = threadIdx.x;

    if (blockIdx.x >= 64) {
        const int n4 = VOCABN * HID / 4;
        int i = (blockIdx.x - 64) * 256 + tid;
        const int stride = 192 * 256;
        for (; i < n4; i += stride) {
            float4 v = ((const float4*)outw_f32)[i];
            ushort4 o;
            o.x = f2bf(v.x); o.y = f2bf(v.y); o.z = f2bf(v.z); o.w = f2bf(v.w);
            ((ushort4*)outw_bf)[i] = o;
        }
        return;
    }

    int lane = tid & 63;
    int wq   = tid >> 6;
    int l15  = lane & 15, l4 = lane >> 4;
    int m0   = blockIdx.x * 16;
    int b    = wq * 16 + l15;
    int mb   = m0 + l4 * 4;

    for (int i = 0; i < 24; ++i) {
        int sb = wq * 24 + i;
        int kt = sb / 3, g = sb % 3;
        const unsigned short* src =
            Whh + (size_t)(g * HID + m0 + l15) * HID + kt * 32 + l4 * 8;
        gld_lds16(src, Wlds + sb * 512);
    }

    float hp[4];
    {
        float4 h4 = *(const float4*)(enc_h + (size_t)b * HID + mb);
        hp[0] = h4.x; hp[1] = h4.y; hp[2] = h4.z; hp[3] = h4.w;
    }
    float bhr[4], bhz[4], bhn[4];
    {
        float4 r4 = *(const float4*)(b_hh + mb);
        float4 z4 = *(const float4*)(b_hh + HID + mb);
        float4 n4 = *(const float4*)(b_hh + 2 * HID + mb);
        bhr[0]=r4.x; bhr[1]=r4.y; bhr[2]=r4.z; bhr[3]=r4.w;
        bhz[0]=z4.x; bhz[1]=z4.y; bhz[2]=z4.z; bhz[3]=z4.w;
        bhn[0]=n4.x; bhn[1]=n4.y; bhn[2]=n4.z; bhn[3]=n4.w;
    }
    __syncthreads();

    int arow16 = b * 128 + l4;

    for (int t = 0; t < T_STEPS; ++t) {
        const float* gib = gi + (size_t)t * BATCH * G3 + (size_t)b * G3;
        float4 giR = *(const float4*)(gib + mb);
        float4 giZ = *(const float4*)(gib + HID + mb);
        float4 giN = *(const float4*)(gib + 2 * HID + mb);
        float gr4[4] = {giR.x, giR.y, giR.z, giR.w};
        float gz4[4] = {giZ.x, giZ.y, giZ.z, giZ.w};
        float gn4[4] = {giN.x, giN.y, giN.z, giN.w};

        if (t > 0) {
            if (tid < 64) {
                while (__hip_atomic_load(flags + tid, __ATOMIC_RELAXED,
                                         __HIP_MEMORY_SCOPE_AGENT) < (unsigned)t) {}
            }
            __builtin_amdgcn_sched_barrier(0);
            __syncthreads();
            asm volatile("" ::: "memory");
        }

        const unsigned short* Asrc = (t == 0) ? h0b : (Hall + (size_t)(t - 1) * BATCH * HID);
        const bf16x8* A16 = (const bf16x8*)Asrc;

        bf16x8 hreg[32];
#pragma unroll
        for (int kt = 0; kt < 32; ++kt) hreg[kt] = A16[arow16 + kt * 4];

        f32x4 acc[3];
#pragma unroll
        for (int g = 0; g < 3; ++g) acc[g] = (f32x4){0.f, 0.f, 0.f, 0.f};

#pragma unroll
        for (int kt = 0; kt < 32; ++kt) {
#pragma unroll
            for (int g = 0; g < 3; ++g) {
                bf16x8 wfrag = *(const bf16x8*)(Wlds + ((size_t)(kt * 3 + g) * 64 + lane) * 8);
                acc[g] = __builtin_amdgcn_mfma_f32_16x16x32_bf16(wfrag, hreg[kt], acc[g], 0, 0, 0);
            }
        }

        unsigned long long pack = 0;
#pragma unroll
        for (int j = 0; j < 4; ++j) {
            float r = 1.f / (1.f + __expf(-(gr4[j] + acc[0][j] + bhr[j])));
            float z = 1.f / (1.f + __expf(-(gz4[j] + acc[1][j] + bhz[j])));
            float e2 = __expf(2.f * (gn4[j] + r * (acc[2][j] + bhn[j])));
            float n = 1.f - 2.f / (e2 + 1.f);   // tanh
            float hnew = (1.f - z) * n + z * hp[j];
            hp[j] = hnew;
            pack |= (unsigned long long)f2bf(hnew) << (16 * j);
        }
        __hip_atomic_store((unsigned long long*)(Hall + (size_t)t * BATCH * HID +
                                                 (size_t)b * HID + mb),
                           pack, __ATOMIC_RELAXED, __HIP_MEMORY_SCOPE_AGENT);
        if (t == T_STEPS - 1) {
            float4 hf = {hp[0], hp[1], hp[2], hp[3]};
            *(float4*)(h_final + (size_t)b * HID + mb) = hf;
        }

        if (t < T_STEPS - 1) {
            __syncthreads();
            if (tid == 0)
                __hip_atomic_store(flags + blockIdx.x, (unsigned)(t + 1),
                                   __ATOMIC_RELAXED, __HIP_MEMORY_SCOPE_AGENT);
        }
    }
}

// ---------------------------------------------------------------- softmax partial reduce
// pstatT [NPART][ROWS] indexed by unpermuted gr; stats indexed by prow.
__global__ __launch_bounds__(64) void lsm_reduce(const float2* __restrict__ pstatT,
                                                 float2* __restrict__ stats) {
    int lane = threadIdx.x;
    int r = blockIdx.x;                       // prow = b*30 + t
    int gr = (r % T_STEPS) * 64 + (r / T_STEPS);
    float m = -1e30f;
    for (int i = lane; i < NPART; i += 64) m = fmaxf(m, pstatT[(size_t)i * ROWS + gr].x);
#pragma unroll
    for (int off = 1; off < 64; off <<= 1) m = fmaxf(m, __shfl_xor(m, off, 64));
    float s = 0.f;
    for (int i = lane; i < NPART; i += 64) {
        float2 t = pstatT[(size_t)i * ROWS + gr];
        s += t.y * __expf(t.x - m);
    }
#pragma unroll
    for (int off = 1; off < 64; off <<= 1) s += __shfl_xor(s, off, 64);
    if (lane == 0) stats[r] = make_float2(m, logf(s));
}

// ---------------------------------------------------------------- apply: out -= mx + logZ
__global__ __launch_bounds__(256) void lsm_apply(float* __restrict__ out,
                                                 const float2* __restrict__ stats) {
    int i = blockIdx.x * 256 + threadIdx.x;
    int stride = gridDim.x * 256;
    const int total4 = ROWS * VOCABN / 4;
    for (; i < total4; i += stride) {
        int row = i / (VOCABN / 4);
        float2 st = stats[row];
        float c = st.x + st.y;
        float4 v = ((float4*)out)[i];
        v.x -= c; v.y -= c; v.z -= c; v.w -= c;
        ((float4*)out)[i] = v;
    }
}

// ----------------------------------------------------------------
extern "C" void kernel_launch(void* const* d_in, const int* in_sizes, int n_in,
                              void* d_out, int out_size, void* d_ws, size_t ws_size,
                              hipStream_t stream) {
    const float* enc_h  = (const float*)d_in[1];
    const int*   target = (const int*)d_in[2];
    const float* emb    = (const float*)d_in[3];
    const float* w_ih   = (const float*)d_in[4];
    const float* w_hh   = (const float*)d_in[5];
    const float* b_ih   = (const float*)d_in[6];
    const float* b_hh   = (const float*)d_in[7];
    const float* out_w  = (const float*)d_in[8];
    const float* out_b  = (const float*)d_in[9];
    float* out = (float*)d_out;

    char* p = (char*)d_ws;
    unsigned short* Xb   = (unsigned short*)p; p += (size_t)ROWS * HID * 2;
    unsigned short* Wih  = (unsigned short*)p; p += (size_t)G3 * HID * 2;
    unsigned short* OutW = (unsigned short*)p; p += (size_t)VOCABN * HID * 2;
    unsigned short* Hall = (unsigned short*)p; p += (size_t)ROWS_PAD * HID * 2;
    float* gi   = (float*)p; p += (size_t)ROWS * G3 * 4;
    unsigned short* Whhb = (unsigned short*)p; p += (size_t)G3 * HID * 2;
    unsigned short* h0b  = (unsigned short*)p; p += (size_t)BATCH * HID * 2;
    float2* stats = (float2*)p; p += (size_t)ROWS * 8;
    unsigned int* bar = (unsigned int*)p; p += 64 * sizeof(unsigned int);
    float2* pstatT = (float2*)Xb;   // [500][1920] = 7.68 MB, overlays Xb+Wih (dead after gi GEMM)

    f32_to_bf16<<<768, 256, 0, stream>>>(w_ih, Wih, G3 * HID / 4);
    f32_to_bf16<<<768, 256, 0, stream>>>(w_hh, Whhb, G3 * HID / 4);
    f32_to_bf16<<<64, 256, 0, stream>>>(enc_h, h0b, BATCH * HID / 4);
    embed_relu_bf16<<<ROWS, 256, 0, stream>>>(target, emb, Xb);
    init_bar<<<1, 64, 0, stream>>>(bar);

    gemm_mfma_bt<<<dim3(G3 / 128, ROWS / 128), 256, 0, stream>>>(Xb, Wih, b_ih, gi, G3, HID);

    {
        const unsigned short* a0 = h0b;
        const float* a1 = enc_h;
        const unsigned short* a2 = Whhb;
        const float* a3 = b_hh;
        const float* a4 = gi;
        unsigned short* a5 = Hall;
        float* a6 = out + OUT_HID_OFF;
        unsigned int* a7 = bar;
        const float* a8 = out_w;
        unsigned short* a9 = OutW;
        void* args[] = {&a0, &a1, &a2, &a3, &a4, &a5, &a6, &a7, &a8, &a9};
        hipLaunchCooperativeKernel((void*)gru_persistent, dim3(256), dim3(256),
                                   args, 0, stream);
    }

    gemm_logits256<<<dim3(ROWS_PAD / 256, VOCABN / 256), 512, 0, stream>>>(Hall, OutW, out_b,
                                                                           out, pstatT);
    lsm_reduce<<<ROWS, 64, 0, stream>>>(pstatT, stats);
    lsm_apply<<<2048, 256, 0, stream>>>(out, stats);
}

// Round 16
// 508.095 us; speedup vs baseline: 1.2280x; 1.0844x over previous
//
#include <hip/hip_runtime.h>
#include <math.h>

#define T_STEPS 30
#define BATCH   64
#define HID     1024
#define VOCABN  32000
#define G3      3072
#define ROWS    (T_STEPS * BATCH)   // 1920
#define ROWS_PAD 2048
#define OUT_HID_OFF ((size_t)BATCH * T_STEPS * VOCABN)  // 61,440,000

typedef __attribute__((ext_vector_type(8))) short bf16x8;
typedef __attribute__((ext_vector_type(4))) float f32x4;

__device__ __forceinline__ unsigned short f2bf(float f) {
    union { float f; unsigned u; } x; x.f = f;
    unsigned r = x.u + 0x7fffu + ((x.u >> 16) & 1u);
    return (unsigned short)(r >> 16);
}
__device__ __forceinline__ float bf2f(unsigned short u) {
    union { unsigned u; float f; } x; x.u = (unsigned)u << 16;
    return x.f;
}

__device__ __forceinline__ void gld_lds16(const unsigned short* g, unsigned short* l) {
    __builtin_amdgcn_global_load_lds(
        (const __attribute__((address_space(1))) unsigned*)g,
        (__attribute__((address_space(3))) unsigned*)l, 16, 0, 0);
}

// ---------------------------------------------------------------- fp32 -> bf16 (RNE)
__global__ __launch_bounds__(256) void f32_to_bf16(const float* __restrict__ src,
                                                   unsigned short* __restrict__ dst, int n4) {
    int i = blockIdx.x * 256 + threadIdx.x;
    int stride = gridDim.x * 256;
    for (; i < n4; i += stride) {
        float4 v = ((const float4*)src)[i];
        ushort4 o;
        o.x = f2bf(v.x); o.y = f2bf(v.y); o.z = f2bf(v.z); o.w = f2bf(v.w);
        ((ushort4*)dst)[i] = o;
    }
}

// ---------------------------------------------------------------- X = relu(emb[tok]) -> bf16
__global__ __launch_bounds__(256) void embed_relu_bf16(const int* __restrict__ target,
                                                       const float* __restrict__ emb,
                                                       unsigned short* __restrict__ X) {
    int bid = blockIdx.x;           // t*64 + b
    int t = bid >> 6, b = bid & 63;
    int tok = (t == 0) ? 0 : target[b * T_STEPS + (t - 1)];
    const float4* src = (const float4*)(emb + (size_t)tok * HID);
    float4 v = src[threadIdx.x];
    ushort4 o;
    o.x = f2bf(fmaxf(v.x, 0.f)); o.y = f2bf(fmaxf(v.y, 0.f));
    o.z = f2bf(fmaxf(v.z, 0.f)); o.w = f2bf(fmaxf(v.w, 0.f));
    ((ushort4*)(X + (size_t)bid * HID))[threadIdx.x] = o;
}

// ---------------------------------------------------------------- barrier flags init (64 flags)
__global__ void init_bar(unsigned int* bar) {
    if (threadIdx.x < 64) bar[threadIdx.x] = 0u;
}

// ---------------------------------------------------------------- gi GEMM (unchanged 128^2)
__global__ __launch_bounds__(256) void gemm_mfma_bt(const unsigned short* __restrict__ A,
                                                    const unsigned short* __restrict__ W,
                                                    const float* __restrict__ bias,
                                                    float* __restrict__ out,
                                                    int N, int K) {
    __shared__ unsigned short As[128 * 64];
    __shared__ unsigned short Bs[128 * 64];
    int tid  = threadIdx.x;
    int lane = tid & 63;
    int wid  = tid >> 6;
    int wm   = wid >> 1, wn = wid & 1;
    const int bM = blockIdx.y * 128;
    const int bN = blockIdx.x * 128;

    f32x4 acc[4][4];
#pragma unroll
    for (int i = 0; i < 4; ++i)
#pragma unroll
        for (int j = 0; j < 4; ++j) acc[i][j] = (f32x4){0.f, 0.f, 0.f, 0.f};

    int sr[4], sc[4];
#pragma unroll
    for (int q = 0; q < 4; ++q) {
        sr[q] = (wid * 4 + q) * 8 + (lane >> 3);
        sc[q] = (lane & 7) ^ (sr[q] & 7);
    }

    for (int kt = 0; kt < K; kt += 64) {
        __syncthreads();
#pragma unroll
        for (int q = 0; q < 4; ++q) {
            gld_lds16(A + (size_t)(bM + sr[q]) * K + kt + sc[q] * 8, As + (wid * 4 + q) * 512);
            gld_lds16(W + (size_t)(bN + sr[q]) * K + kt + sc[q] * 8, Bs + (wid * 4 + q) * 512);
        }
        __syncthreads();

#pragma unroll
        for (int ks = 0; ks < 2; ++ks) {
            bf16x8 a[4], b[4];
#pragma unroll
            for (int mf = 0; mf < 4; ++mf) {
                int r  = wm * 64 + mf * 16 + (lane & 15);
                int ch = (ks * 4 + (lane >> 4)) ^ (r & 7);
                a[mf] = *(const bf16x8*)(As + r * 64 + ch * 8);
            }
#pragma unroll
            for (int nf = 0; nf < 4; ++nf) {
                int r  = wn * 64 + nf * 16 + (lane & 15);
                int ch = (ks * 4 + (lane >> 4)) ^ (r & 7);
                b[nf] = *(const bf16x8*)(Bs + r * 64 + ch * 8);
            }
#pragma unroll
            for (int mf = 0; mf < 4; ++mf)
#pragma unroll
                for (int nf = 0; nf < 4; ++nf)
                    acc[mf][nf] = __builtin_amdgcn_mfma_f32_16x16x32_bf16(
                        a[mf], b[nf], acc[mf][nf], 0, 0, 0);
        }
    }

    int rif = (lane >> 4) * 4;
    int col = lane & 15;
#pragma unroll
    for (int mf = 0; mf < 4; ++mf) {
#pragma unroll
        for (int j = 0; j < 4; ++j) {
            int gr = bM + wm * 64 + mf * 16 + rif + j;
#pragma unroll
            for (int nf = 0; nf < 4; ++nf) {
                int gc = bN + wn * 64 + nf * 16 + col;
                out[(size_t)gr * N + gc] = acc[mf][nf][j] + bias[gc];
            }
        }
    }
}

// ---------------------------------------------------------------- logits GEMM: 256^2 tile,
// r14 ring pipeline, clean epilogue (no stats). BF16OUT=true: write bf16 logits
// to scratch (half traffic); false: write fp32 direct to out (ws fallback).
template <bool BF16OUT>
__global__ __launch_bounds__(512) void gemm_logits256(const unsigned short* __restrict__ A,
                                                      const unsigned short* __restrict__ W,
                                                      const float* __restrict__ bias,
                                                      float* __restrict__ out,
                                                      unsigned short* __restrict__ scratch) {
    __shared__ unsigned short As[4][256 * 32];   // 16 KB per slot
    __shared__ unsigned short Bs[4][256 * 32];
    const int bM = blockIdx.x * 256;
    const int bN = blockIdx.y * 256;

    int tid  = threadIdx.x;
    int lane = tid & 63;
    int wid  = tid >> 6;         // 0..7
    int wm   = wid >> 2;         // 0..1 -> 128 M-rows
    int wn   = wid & 3;          // 0..3 -> 64 N-cols
    int l15  = lane & 15, l4 = lane >> 4;

    size_t pA[2], pB[2];
    int ldst[2];
#pragma unroll
    for (int i = 0; i < 2; ++i) {
        int c = wid * 128 + i * 64 + lane;
        int r = c >> 2, cc = c & 3;
        int so = (cc ^ ((r >> 1) & 3)) * 8;
        pA[i] = (size_t)(bM + r) * HID + so;
        pB[i] = (size_t)(bN + r) * HID + so;
        ldst[i] = wid * 1024 + i * 512;
    }

    f32x4 acc[8][4];
#pragma unroll
    for (int i = 0; i < 8; ++i)
#pragma unroll
        for (int j = 0; j < 4; ++j) acc[i][j] = (f32x4){0.f, 0.f, 0.f, 0.f};

    int chsw = (l4 ^ ((l15 >> 1) & 3)) * 8;
    int aoff[8], boff[4];
#pragma unroll
    for (int mf = 0; mf < 8; ++mf) aoff[mf] = (wm * 128 + mf * 16 + l15) * 32 + chsw;
#pragma unroll
    for (int nf = 0; nf < 4; ++nf) boff[nf] = (wn * 64 + nf * 16 + l15) * 32 + chsw;

    auto issue = [&](int s) {
        int slot = s & 3;
#pragma unroll
        for (int i = 0; i < 2; ++i)
            gld_lds16(A + pA[i] + s * 32, &As[slot][ldst[i]]);
#pragma unroll
        for (int i = 0; i < 2; ++i)
            gld_lds16(W + pB[i] + s * 32, &Bs[slot][ldst[i]]);
    };

    issue(0); issue(1); issue(2);

#pragma unroll 1
    for (int s = 0; s < 32; ++s) {
        if (s < 30)       asm volatile("s_waitcnt vmcnt(8)" ::: "memory");
        else if (s == 30) asm volatile("s_waitcnt vmcnt(4)" ::: "memory");
        else              asm volatile("s_waitcnt vmcnt(0)" ::: "memory");
        __builtin_amdgcn_s_barrier();
        asm volatile("" ::: "memory");
        __builtin_amdgcn_sched_barrier(0);
        if (s < 29) issue(s + 3);

        int slot = s & 3;
        const unsigned short* ab = As[slot];
        const unsigned short* bb = Bs[slot];
        bf16x8 a[8], b[4];
#pragma unroll
        for (int mf = 0; mf < 8; ++mf) a[mf] = *(const bf16x8*)(ab + aoff[mf]);
#pragma unroll
        for (int nf = 0; nf < 4; ++nf) b[nf] = *(const bf16x8*)(bb + boff[nf]);
        __builtin_amdgcn_s_setprio(1);
#pragma unroll
        for (int mf = 0; mf < 8; ++mf)
#pragma unroll
            for (int nf = 0; nf < 4; ++nf)
                acc[mf][nf] = __builtin_amdgcn_mfma_f32_16x16x32_bf16(
                    a[mf], b[nf], acc[mf][nf], 0, 0, 0);
        __builtin_amdgcn_s_setprio(0);
    }

    int col = l15;
    float b4[4];
#pragma unroll
    for (int nf = 0; nf < 4; ++nf) b4[nf] = bias[bN + wn * 64 + nf * 16 + col];
    int rif = l4 * 4;
#pragma unroll
    for (int mf = 0; mf < 8; ++mf) {
#pragma unroll
        for (int j = 0; j < 4; ++j) {
            int gr = bM + wm * 128 + mf * 16 + rif + j;
            if (gr < ROWS) {
                int t = gr >> 6, b_ = gr & 63;
                size_t rowoff = ((size_t)b_ * T_STEPS + t) * (size_t)VOCABN;
#pragma unroll
                for (int nf = 0; nf < 4; ++nf) {
                    float v = acc[mf][nf][j] + b4[nf];
                    int gc = bN + wn * 64 + nf * 16 + col;
                    if (BF16OUT) scratch[rowoff + gc] = f2bf(v);
                    else         out[rowoff + gc] = v;
                }
            }
        }
    }
}

// ---------------------------------------------------------------- persistent 30-step GRU
// (r15: blocks 0-63 recurrence; 64-255 OutW convert, hidden under recurrence)
__global__ __launch_bounds__(256, 1) void gru_persistent(
    const unsigned short* __restrict__ h0b,
    const float* __restrict__ enc_h,
    const unsigned short* __restrict__ Whh,
    const float* __restrict__ b_hh,
    const float* __restrict__ gi,
    unsigned short* __restrict__ Hall,
    float* __restrict__ h_final,
    unsigned int* __restrict__ flags,
    const float* __restrict__ outw_f32,
    unsigned short* __restrict__ outw_bf)
{
    __shared__ unsigned short Wlds[48 * 1024];   // 96 KB
    int tid  = threadIdx.x;

    if (blockIdx.x >= 64) {
        const int n4 = VOCABN * HID / 4;
        int i = (blockIdx.x - 64) * 256 + tid;
        const int stride = 192 * 256;
        for (; i < n4; i += stride) {
            float4 v = ((const float4*)outw_f32)[i];
            ushort4 o;
            o.x = f2bf(v.x); o.y = f2bf(v.y); o.z = f2bf(v.z); o.w = f2bf(v.w);
            ((ushort4*)outw_bf)[i] = o;
        }
        return;
    }

    int lane = tid & 63;
    int wq   = tid >> 6;
    int l15  = lane & 15, l4 = lane >> 4;
    int m0   = blockIdx.x * 16;
    int b    = wq * 16 + l15;
    int mb   = m0 + l4 * 4;

    for (int i = 0; i < 24; ++i) {
        int sb = wq * 24 + i;
        int kt = sb / 3, g = sb % 3;
        const unsigned short* src =
            Whh + (size_t)(g * HID + m0 + l15) * HID + kt * 32 + l4 * 8;
        gld_lds16(src, Wlds + sb * 512);
    }

    float hp[4];
    {
        float4 h4 = *(const float4*)(enc_h + (size_t)b * HID + mb);
        hp[0] = h4.x; hp[1] = h4.y; hp[2] = h4.z; hp[3] = h4.w;
    }
    float bhr[4], bhz[4], bhn[4];
    {
        float4 r4 = *(const float4*)(b_hh + mb);
        float4 z4 = *(const float4*)(b_hh + HID + mb);
        float4 n4 = *(const float4*)(b_hh + 2 * HID + mb);
        bhr[0]=r4.x; bhr[1]=r4.y; bhr[2]=r4.z; bhr[3]=r4.w;
        bhz[0]=z4.x; bhz[1]=z4.y; bhz[2]=z4.z; bhz[3]=z4.w;
        bhn[0]=n4.x; bhn[1]=n4.y; bhn[2]=n4.z; bhn[3]=n4.w;
    }
    __syncthreads();

    int arow16 = b * 128 + l4;

    for (int t = 0; t < T_STEPS; ++t) {
        const float* gib = gi + (size_t)t * BATCH * G3 + (size_t)b * G3;
        float4 giR = *(const float4*)(gib + mb);
        float4 giZ = *(const float4*)(gib + HID + mb);
        float4 giN = *(const float4*)(gib + 2 * HID + mb);
        float gr4[4] = {giR.x, giR.y, giR.z, giR.w};
        float gz4[4] = {giZ.x, giZ.y, giZ.z, giZ.w};
        float gn4[4] = {giN.x, giN.y, giN.z, giN.w};

        if (t > 0) {
            if (tid < 64) {
                while (__hip_atomic_load(flags + tid, __ATOMIC_RELAXED,
                                         __HIP_MEMORY_SCOPE_AGENT) < (unsigned)t) {}
            }
            __builtin_amdgcn_sched_barrier(0);
            __syncthreads();
            asm volatile("" ::: "memory");
        }

        const unsigned short* Asrc = (t == 0) ? h0b : (Hall + (size_t)(t - 1) * BATCH * HID);
        const bf16x8* A16 = (const bf16x8*)Asrc;

        bf16x8 hreg[32];
#pragma unroll
        for (int kt = 0; kt < 32; ++kt) hreg[kt] = A16[arow16 + kt * 4];

        f32x4 acc[3];
#pragma unroll
        for (int g = 0; g < 3; ++g) acc[g] = (f32x4){0.f, 0.f, 0.f, 0.f};

#pragma unroll
        for (int kt = 0; kt < 32; ++kt) {
#pragma unroll
            for (int g = 0; g < 3; ++g) {
                bf16x8 wfrag = *(const bf16x8*)(Wlds + ((size_t)(kt * 3 + g) * 64 + lane) * 8);
                acc[g] = __builtin_amdgcn_mfma_f32_16x16x32_bf16(wfrag, hreg[kt], acc[g], 0, 0, 0);
            }
        }

        unsigned long long pack = 0;
#pragma unroll
        for (int j = 0; j < 4; ++j) {
            float r = 1.f / (1.f + __expf(-(gr4[j] + acc[0][j] + bhr[j])));
            float z = 1.f / (1.f + __expf(-(gz4[j] + acc[1][j] + bhz[j])));
            float e2 = __expf(2.f * (gn4[j] + r * (acc[2][j] + bhn[j])));
            float n = 1.f - 2.f / (e2 + 1.f);   // tanh
            float hnew = (1.f - z) * n + z * hp[j];
            hp[j] = hnew;
            pack |= (unsigned long long)f2bf(hnew) << (16 * j);
        }
        __hip_atomic_store((unsigned long long*)(Hall + (size_t)t * BATCH * HID +
                                                 (size_t)b * HID + mb),
                           pack, __ATOMIC_RELAXED, __HIP_MEMORY_SCOPE_AGENT);
        if (t == T_STEPS - 1) {
            float4 hf = {hp[0], hp[1], hp[2], hp[3]};
            *(float4*)(h_final + (size_t)b * HID + mb) = hf;
        }

        if (t < T_STEPS - 1) {
            __syncthreads();
            if (tid == 0)
                __hip_atomic_store(flags + blockIdx.x, (unsigned)(t + 1),
                                   __ATOMIC_RELAXED, __HIP_MEMORY_SCOPE_AGENT);
        }
    }
}

// ---------------------------------------------------------------- fused log-softmax from bf16
// scratch: one block per row. Load bf16 row -> LDS (64 KB, 2 blocks/CU) while
// computing online (max,sumexp) from the SAME bf16 values; write fp32 out.
// HBM: 64 KB read + 128 KB write per row (vs 3x128 KB fp32).
__global__ __launch_bounds__(256) void lsm_fused_bf16(const unsigned short* __restrict__ scratch,
                                                      float* __restrict__ out) {
    __shared__ bf16x8 srow[4000];    // 64 KB
    __shared__ float2 sred[4];
    __shared__ float sc;
    const bf16x8* src = (const bf16x8*)(scratch + (size_t)blockIdx.x * VOCABN);
    float* dst = out + (size_t)blockIdx.x * VOCABN;
    int tid = threadIdx.x;
    int lane = tid & 63, w = tid >> 6;

    float m = -1e30f, s = 0.f;
    for (int i = tid; i < 4000; i += 256) {
        bf16x8 v = src[i];
        srow[i] = v;
        float f[8];
#pragma unroll
        for (int j = 0; j < 8; ++j) f[j] = bf2f((unsigned short)v[j]);
        float cm = f[0];
#pragma unroll
        for (int j = 1; j < 8; ++j) cm = fmaxf(cm, f[j]);
        if (cm > m) { s *= __expf(m - cm); m = cm; }
#pragma unroll
        for (int j = 0; j < 8; ++j) s += __expf(f[j] - m);
    }
#pragma unroll
    for (int off = 1; off < 64; off <<= 1) {
        float om = __shfl_xor(m, off, 64);
        float os = __shfl_xor(s, off, 64);
        float nm = fmaxf(m, om);
        s = s * __expf(m - nm) + os * __expf(om - nm);
        m = nm;
    }
    if (lane == 0) sred[w] = make_float2(m, s);
    __syncthreads();
    if (tid == 0) {
        float fm = sred[0].x, fs = sred[0].y;
#pragma unroll
        for (int k = 1; k < 4; ++k) {
            float om = sred[k].x, os = sred[k].y;
            float nm = fmaxf(fm, om);
            fs = fs * __expf(fm - nm) + os * __expf(om - nm);
            fm = nm;
        }
        sc = fm + logf(fs);
    }
    __syncthreads();
    float c = sc;
    for (int i = tid; i < 4000; i += 256) {
        bf16x8 v = srow[i];
        float4 o0, o1;
        o0.x = bf2f((unsigned short)v[0]) - c; o0.y = bf2f((unsigned short)v[1]) - c;
        o0.z = bf2f((unsigned short)v[2]) - c; o0.w = bf2f((unsigned short)v[3]) - c;
        o1.x = bf2f((unsigned short)v[4]) - c; o1.y = bf2f((unsigned short)v[5]) - c;
        o1.z = bf2f((unsigned short)v[6]) - c; o1.w = bf2f((unsigned short)v[7]) - c;
        ((float4*)dst)[i * 2] = o0;
        ((float4*)dst)[i * 2 + 1] = o1;
    }
}

// ---------------------------------------------------------------- fp32 fallback log-softmax (r14)
__global__ __launch_bounds__(256) void lsm_fused(float* __restrict__ out) {
    float4* p4 = (float4*)(out + (size_t)blockIdx.x * VOCABN);
    int tid = threadIdx.x;
    int lane = tid & 63, w = tid >> 6;
    __shared__ float2 sred[4];
    __shared__ float sc;

    float m = -1e30f, s = 0.f;
    for (int i = tid; i < VOCABN / 4; i += 256) {
        float4 v = p4[i];
        float cm = fmaxf(fmaxf(v.x, v.y), fmaxf(v.z, v.w));
        if (cm > m) { s *= __expf(m - cm); m = cm; }
        s += __expf(v.x - m) + __expf(v.y - m) + __expf(v.z - m) + __expf(v.w - m);
    }
#pragma unroll
    for (int off = 1; off < 64; off <<= 1) {
        float om = __shfl_xor(m, off, 64);
        float os = __shfl_xor(s, off, 64);
        float nm = fmaxf(m, om);
        s = s * __expf(m - nm) + os * __expf(om - nm);
        m = nm;
    }
    if (lane == 0) sred[w] = make_float2(m, s);
    __syncthreads();
    if (tid == 0) {
        float fm = sred[0].x, fs = sred[0].y;
#pragma unroll
        for (int k = 1; k < 4; ++k) {
            float om = sred[k].x, os = sred[k].y;
            float nm = fmaxf(fm, om);
            fs = fs * __expf(fm - nm) + os * __expf(om - nm);
            fm = nm;
        }
        sc = fm + logf(fs);
    }
    __syncthreads();
    float c = sc;
    for (int i = tid; i < VOCABN / 4; i += 256) {
        float4 v = p4[i];
        v.x -= c; v.y -= c; v.z -= c; v.w -= c;
        p4[i] = v;
    }
}

// ----------------------------------------------------------------
extern "C" void kernel_launch(void* const* d_in, const int* in_sizes, int n_in,
                              void* d_out, int out_size, void* d_ws, size_t ws_size,
                              hipStream_t stream) {
    const float* enc_h  = (const float*)d_in[1];
    const int*   target = (const int*)d_in[2];
    const float* emb    = (const float*)d_in[3];
    const float* w_ih   = (const float*)d_in[4];
    const float* w_hh   = (const float*)d_in[5];
    const float* b_ih   = (const float*)d_in[6];
    const float* b_hh   = (const float*)d_in[7];
    const float* out_w  = (const float*)d_in[8];
    const float* out_b  = (const float*)d_in[9];
    float* out = (float*)d_out;

    char* p0 = (char*)d_ws;
    char* p = p0;
    unsigned short* Xb   = (unsigned short*)p; p += (size_t)ROWS * HID * 2;
    unsigned short* Wih  = (unsigned short*)p; p += (size_t)G3 * HID * 2;
    unsigned short* OutW = (unsigned short*)p; p += (size_t)VOCABN * HID * 2;
    unsigned short* Hall = (unsigned short*)p; p += (size_t)ROWS_PAD * HID * 2;
    float* gi   = (float*)p; p += (size_t)ROWS * G3 * 4;
    unsigned short* Whhb = (unsigned short*)p; p += (size_t)G3 * HID * 2;
    unsigned short* h0b  = (unsigned short*)p; p += (size_t)BATCH * HID * 2;
    unsigned int* bar = (unsigned int*)p; p += 256 * sizeof(unsigned int);
    unsigned short* lscratch = (unsigned short*)p; p += (size_t)ROWS * VOCABN * 2;  // 122.88 MB
    const bool use_bf16 = ((size_t)(p - p0) <= ws_size);

    f32_to_bf16<<<768, 256, 0, stream>>>(w_ih, Wih, G3 * HID / 4);
    f32_to_bf16<<<768, 256, 0, stream>>>(w_hh, Whhb, G3 * HID / 4);
    f32_to_bf16<<<64, 256, 0, stream>>>(enc_h, h0b, BATCH * HID / 4);
    embed_relu_bf16<<<ROWS, 256, 0, stream>>>(target, emb, Xb);
    init_bar<<<1, 64, 0, stream>>>(bar);

    gemm_mfma_bt<<<dim3(G3 / 128, ROWS / 128), 256, 0, stream>>>(Xb, Wih, b_ih, gi, G3, HID);

    {
        const unsigned short* a0 = h0b;
        const float* a1 = enc_h;
        const unsigned short* a2 = Whhb;
        const float* a3 = b_hh;
        const float* a4 = gi;
        unsigned short* a5 = Hall;
        float* a6 = out + OUT_HID_OFF;
        unsigned int* a7 = bar;
        const float* a8 = out_w;
        unsigned short* a9 = OutW;
        void* args[] = {&a0, &a1, &a2, &a3, &a4, &a5, &a6, &a7, &a8, &a9};
        hipLaunchCooperativeKernel((void*)gru_persistent, dim3(256), dim3(256),
                                   args, 0, stream);
    }

    if (use_bf16) {
        gemm_logits256<true><<<dim3(ROWS_PAD / 256, VOCABN / 256), 512, 0, stream>>>(
            Hall, OutW, out_b, out, lscratch);
        lsm_fused_bf16<<<ROWS, 256, 0, stream>>>(lscratch, out);
    } else {
        gemm_logits256<false><<<dim3(ROWS_PAD / 256, VOCABN / 256), 512, 0, stream>>>(
            Hall, OutW, out_b, out, nullptr);
        lsm_fused<<<ROWS, 256, 0, stream>>>(out);
    }
}